// Round 14
// baseline (187.844 us; speedup 1.0000x reference)
//
#include <hip/hip_runtime.h>
#include <hip/hip_bf16.h>
#include <hip/hip_fp16.h>
#include <cstdint>

static constexpr int NB  = 8;
static constexpr int HH  = 96;
static constexpr int WW  = 96;
static constexpr int NP  = 9216;   // 96*96
static constexpr int NPK = 576;    // 24*24

using bf8 = __attribute__((ext_vector_type(8))) short;
using f4  = __attribute__((ext_vector_type(4))) float;

__device__ __forceinline__ unsigned pack_bf2(float a, float b) {
    __hip_bfloat162 h = __float22bfloat162_rn(make_float2(a, b));
    unsigned u; __builtin_memcpy(&u, &h, 4);
    return u;
}
__device__ __forceinline__ unsigned short f2bfu(float f) {
    __hip_bfloat16 h = __float2bfloat16(f);
    unsigned short u; __builtin_memcpy(&u, &h, 2);
    return u;
}
__device__ __forceinline__ float bf2f(unsigned short u) {
    unsigned v = (unsigned)u << 16;
    float f; __builtin_memcpy(&f, &v, 4);
    return f;
}
__device__ __forceinline__ float bflo(unsigned p) {
    unsigned v = p << 16; float f; __builtin_memcpy(&f, &v, 4); return f;
}
__device__ __forceinline__ float bfhi(unsigned p) {
    unsigned v = p & 0xffff0000u; float f; __builtin_memcpy(&f, &v, 4); return f;
}

// ---------------------------------------------------------------------------
// Fused qkv+gq conv1x1 with LDS-staged x.  (r12; gq scale now 0.25*log2e)
// ---------------------------------------------------------------------------
__global__ __launch_bounds__(256) void k_qkvgq(
    const float* __restrict__ x,
    const float* __restrict__ qkv_w, const float* __restrict__ qkv_b,
    const float* __restrict__ gq_w,  const float* __restrict__ gq_b,
    unsigned short* __restrict__ qkv_out,   // bf16 (B,192,NP)
    unsigned short* __restrict__ gq_out)    // bf16 (B,64,NP), pre-scaled 0.25*log2e
{
    __shared__ __align__(16) unsigned xl[64 * 64];   // 16KB
    const int tid  = threadIdx.x;
    const int lane = tid & 63, wid = tid >> 6;
    const int quad = blockIdx.x, b = blockIdx.z;
    const int arow = lane & 15, agrp = lane >> 4;

    const float* xb = x + (long long)b * 128 * NP + quad * 64;

#pragma unroll
    for (int it = 0; it < 4; ++it) {
        const int task = tid + 256 * it;
        const int cp = task >> 4, pq = task & 15;
        float4 a = *(const float4*)&xb[(long long)(2 * cp) * NP + pq * 4];
        float4 c = *(const float4*)&xb[(long long)(2 * cp + 1) * NP + pq * 4];
        const int cps = cp ^ ((pq & 7) << 2);
        xl[(pq * 4 + 0) * 64 + cps] = pack_bf2(a.x, c.x);
        xl[(pq * 4 + 1) * 64 + cps] = pack_bf2(a.y, c.y);
        xl[(pq * 4 + 2) * 64 + cps] = pack_bf2(a.z, c.z);
        xl[(pq * 4 + 3) * 64 + cps] = pack_bf2(a.w, c.w);
    }
    __syncthreads();

    uint4 breg[4][4];
#pragma unroll
    for (int kt = 0; kt < 4; ++kt)
#pragma unroll
        for (int i = 0; i < 4; ++i) {
            const int px = arow * 4 + i;
            const int cp = (kt * 16 + agrp * 4) ^ ((arow & 7) << 2);
            breg[kt][i] = *(const uint4*)&xl[px * 64 + cp];
        }

    for (int gi = 0; gi < 4; ++gi) {
        const int grp = wid + gi * 4;
        const bool isgq = grp >= 12;
        const float* wsrc = isgq ? gq_w : qkv_w;
        const float* bsrc = isgq ? gq_b : qkv_b;
        const float wsc = isgq ? 0.36067376022224085f : 1.0f;  // 0.25*log2(e)
        const int och = (isgq ? grp - 12 : grp) * 16;

        bf8 afr[4];
#pragma unroll
        for (int kt = 0; kt < 4; ++kt) {
            const float* wp = wsrc + (long long)(och + arow) * 128 + kt * 32 + agrp * 8;
            int4 t;
            t.x = (int)pack_bf2(wp[0] * wsc, wp[1] * wsc);
            t.y = (int)pack_bf2(wp[2] * wsc, wp[3] * wsc);
            t.z = (int)pack_bf2(wp[4] * wsc, wp[5] * wsc);
            t.w = (int)pack_bf2(wp[6] * wsc, wp[7] * wsc);
            afr[kt] = __builtin_bit_cast(bf8, t);
        }

        f4 acc[4];
#pragma unroll
        for (int i = 0; i < 4; ++i) acc[i] = (f4){0.f, 0.f, 0.f, 0.f};
#pragma unroll
        for (int kt = 0; kt < 4; ++kt)
#pragma unroll
            for (int i = 0; i < 4; ++i)
                acc[i] = __builtin_amdgcn_mfma_f32_16x16x32_bf16(
                    afr[kt], __builtin_bit_cast(bf8, breg[kt][i]), acc[i], 0, 0, 0);

        unsigned short* ob = isgq ? gq_out : qkv_out;
        const int ostride = isgq ? 64 : 192;
#pragma unroll
        for (int r = 0; r < 4; ++r) {
            const int o = och + agrp * 4 + r;
            const float bs = bsrc[o] * wsc;
            const float v0 = acc[0][r] + bs, v1 = acc[1][r] + bs;
            const float v2 = acc[2][r] + bs, v3 = acc[3][r] + bs;
            *(uint2*)&ob[((long long)b * ostride + o) * NP + quad * 64 + arow * 4] =
                make_uint2(pack_bf2(v0, v1), pack_bf2(v2, v3));
        }
    }
}

// ---------------------------------------------------------------------------
// MFMA conv1x1 (generic; gkv f32->f32 and proj bf16->f32).  (unchanged)
// ---------------------------------------------------------------------------
template<int C, int OT, int INBF, int OUTBF>
__global__ __launch_bounds__(256) void k_mfma_conv(
    const void* __restrict__ in0v, const float* __restrict__ w,
    const float* __restrict__ bias, void* __restrict__ outv,
    int np, long long ibs, int storeO, float wscale)
{
    constexpr int KT = C / 32;
    const int tid  = threadIdx.x;
    const int lane = tid & 63, wid = tid >> 6;
    const int b    = blockIdx.z;
    const int obq  = blockIdx.y * (OT * 16);
    const int arow = lane & 15, agrp = lane >> 4;
    const int nquad = np >> 6;

    bf8 afr[OT][KT];
#pragma unroll
    for (int ot = 0; ot < OT; ++ot)
#pragma unroll
        for (int kt = 0; kt < KT; ++kt) {
            const float* wp = w + (long long)(obq + ot * 16 + arow) * C + kt * 32 + agrp * 8;
            int4 t;
            t.x = (int)pack_bf2(wp[0] * wscale, wp[1] * wscale);
            t.y = (int)pack_bf2(wp[2] * wscale, wp[3] * wscale);
            t.z = (int)pack_bf2(wp[4] * wscale, wp[5] * wscale);
            t.w = (int)pack_bf2(wp[6] * wscale, wp[7] * wscale);
            afr[ot][kt] = __builtin_bit_cast(bf8, t);
        }

    const float*          x0f = (const float*)in0v          + (long long)b * (INBF ? 0 : ibs);
    const unsigned short* x0h = (const unsigned short*)in0v + (long long)b * (INBF ? ibs : 0);

    const int quad = blockIdx.x * 4 + wid;
    if (quad >= nquad) return;
    const int p0 = quad * 64 + arow * 4;

    f4 acc[4][OT];
#pragma unroll
    for (int i = 0; i < 4; ++i)
#pragma unroll
        for (int ot = 0; ot < OT; ++ot) acc[i][ot] = (f4){0.f, 0.f, 0.f, 0.f};

#pragma unroll
    for (int kt = 0; kt < KT; ++kt) {
        const long long cbase = kt * 32 + agrp * 8;
        int uu[4][4];
#pragma unroll
        for (int jj = 0; jj < 4; ++jj) {
            if (INBF == 0) {
                float4 a0 = *(const float4*)&x0f[(cbase + 2 * jj) * np + p0];
                float4 a1 = *(const float4*)&x0f[(cbase + 2 * jj + 1) * np + p0];
                uu[0][jj] = (int)pack_bf2(a0.x, a1.x);
                uu[1][jj] = (int)pack_bf2(a0.y, a1.y);
                uu[2][jj] = (int)pack_bf2(a0.z, a1.z);
                uu[3][jj] = (int)pack_bf2(a0.w, a1.w);
            } else {
                ushort4 a0 = *(const ushort4*)&x0h[(cbase + 2 * jj) * np + p0];
                ushort4 a1 = *(const ushort4*)&x0h[(cbase + 2 * jj + 1) * np + p0];
                uu[0][jj] = (int)((unsigned)a0.x | ((unsigned)a1.x << 16));
                uu[1][jj] = (int)((unsigned)a0.y | ((unsigned)a1.y << 16));
                uu[2][jj] = (int)((unsigned)a0.z | ((unsigned)a1.z << 16));
                uu[3][jj] = (int)((unsigned)a0.w | ((unsigned)a1.w << 16));
            }
        }
#pragma unroll
        for (int i = 0; i < 4; ++i) {
            int4 ti = {uu[i][0], uu[i][1], uu[i][2], uu[i][3]};
            bf8 bfr = __builtin_bit_cast(bf8, ti);
#pragma unroll
            for (int ot = 0; ot < OT; ++ot)
                acc[i][ot] = __builtin_amdgcn_mfma_f32_16x16x32_bf16(afr[ot][kt], bfr, acc[i][ot], 0, 0, 0);
        }
    }

#pragma unroll
    for (int ot = 0; ot < OT; ++ot) {
#pragma unroll
        for (int r = 0; r < 4; ++r) {
            const int o = obq + ot * 16 + agrp * 4 + r;
            const float bs = bias[o] * wscale;
            float4 v;
            v.x = acc[0][ot][r] + bs;
            v.y = acc[1][ot][r] + bs;
            v.z = acc[2][ot][r] + bs;
            v.w = acc[3][ot][r] + bs;
            const long long idx = ((long long)b * storeO + o) * np + p0;
            if (OUTBF == 0) {
                *(float4*)&((float*)outv)[idx] = v;
            } else {
                *(uint2*)&((unsigned short*)outv)[idx] =
                    make_uint2(pack_bf2(v.x, v.y), pack_bf2(v.z, v.w));
            }
        }
    }
}

// ---------------------------------------------------------------------------
// Fused am1+am2 (bf16 I/O), unchanged from r13.
// ---------------------------------------------------------------------------
__global__ __launch_bounds__(256) void k_am_fused(
    const unsigned short* __restrict__ dw,   // bf16: q +0, k +64NP, v +128NP
    const float* __restrict__ w1, const float* __restrict__ b1v,
    const float* __restrict__ w2, const float* __restrict__ b2v,
    unsigned short* __restrict__ hi)         // bf16 hilo ch 0..63
{
    __shared__ __align__(16) uint2 abuf[4][1024];

    const int tid  = threadIdx.x;
    const int lane = tid & 63, wid = tid >> 6;
    const int b    = blockIdx.z;
    const int arow = lane & 15, agrp = lane >> 4;

    bf8 afr1[4][2], afr2[4][2];
#pragma unroll
    for (int ot = 0; ot < 4; ++ot)
#pragma unroll
        for (int kt = 0; kt < 2; ++kt) {
            const float* wp1 = w1 + (long long)(ot * 16 + arow) * 64 + kt * 32 + agrp * 8;
            const float* wp2 = w2 + (long long)(ot * 16 + arow) * 64 + kt * 32 + agrp * 8;
            int4 t1, t2;
            t1.x = (int)pack_bf2(wp1[0], wp1[1]);  t2.x = (int)pack_bf2(wp2[0], wp2[1]);
            t1.y = (int)pack_bf2(wp1[2], wp1[3]);  t2.y = (int)pack_bf2(wp2[2], wp2[3]);
            t1.z = (int)pack_bf2(wp1[4], wp1[5]);  t2.z = (int)pack_bf2(wp2[4], wp2[5]);
            t1.w = (int)pack_bf2(wp1[6], wp1[7]);  t2.w = (int)pack_bf2(wp2[6], wp2[7]);
            afr1[ot][kt] = __builtin_bit_cast(bf8, t1);
            afr2[ot][kt] = __builtin_bit_cast(bf8, t2);
        }

    const unsigned short* xq = dw + (long long)b * (192ll * NP);
    const unsigned short* xk = xq + 64ll * NP;
    const unsigned short* xv = xq + 128ll * NP;

    const int quad = blockIdx.x * 4 + wid;
    const int p0 = quad * 64 + arow * 4;

    f4 acc1[4][4];
#pragma unroll
    for (int i = 0; i < 4; ++i)
#pragma unroll
        for (int ot = 0; ot < 4; ++ot) acc1[i][ot] = (f4){0.f, 0.f, 0.f, 0.f};

#pragma unroll
    for (int kt = 0; kt < 2; ++kt) {
        const long long cbase = kt * 32 + agrp * 8;
        int uu[4][4];
#pragma unroll
        for (int jj = 0; jj < 4; ++jj) {
            ushort4 a0 = *(const ushort4*)&xq[(cbase + 2 * jj) * NP + p0];
            ushort4 a1 = *(const ushort4*)&xq[(cbase + 2 * jj + 1) * NP + p0];
            ushort4 y0 = *(const ushort4*)&xk[(cbase + 2 * jj) * NP + p0];
            ushort4 y1 = *(const ushort4*)&xk[(cbase + 2 * jj + 1) * NP + p0];
            uu[0][jj] = (int)pack_bf2(bf2f(a0.x) * bf2f(y0.x), bf2f(a1.x) * bf2f(y1.x));
            uu[1][jj] = (int)pack_bf2(bf2f(a0.y) * bf2f(y0.y), bf2f(a1.y) * bf2f(y1.y));
            uu[2][jj] = (int)pack_bf2(bf2f(a0.z) * bf2f(y0.z), bf2f(a1.z) * bf2f(y1.z));
            uu[3][jj] = (int)pack_bf2(bf2f(a0.w) * bf2f(y0.w), bf2f(a1.w) * bf2f(y1.w));
        }
#pragma unroll
        for (int i = 0; i < 4; ++i) {
            int4 ti = {uu[i][0], uu[i][1], uu[i][2], uu[i][3]};
            bf8 bfr = __builtin_bit_cast(bf8, ti);
#pragma unroll
            for (int ot = 0; ot < 4; ++ot)
                acc1[i][ot] = __builtin_amdgcn_mfma_f32_16x16x32_bf16(afr1[ot][kt], bfr, acc1[i][ot], 0, 0, 0);
        }
    }

#pragma unroll
    for (int i = 0; i < 4; ++i)
#pragma unroll
        for (int ot = 0; ot < 4; ++ot) {
            const int ch0 = ot * 16 + agrp * 4;
            float v0 = acc1[i][ot][0] + b1v[ch0 + 0];
            float v1 = acc1[i][ot][1] + b1v[ch0 + 1];
            float v2 = acc1[i][ot][2] + b1v[ch0 + 2];
            float v3 = acc1[i][ot][3] + b1v[ch0 + 3];
            v0 = v0 / (1.f + __expf(-v0));
            v1 = v1 / (1.f + __expf(-v1));
            v2 = v2 / (1.f + __expf(-v2));
            v3 = v3 / (1.f + __expf(-v3));
            const int c2 = ot * 4 + agrp;
            abuf[wid][(arow * 4 + i) * 16 + (c2 ^ arow)] =
                make_uint2(pack_bf2(v0, v1), pack_bf2(v2, v3));
        }

    f4 acc2[4][4];
#pragma unroll
    for (int i = 0; i < 4; ++i)
#pragma unroll
        for (int ot = 0; ot < 4; ++ot) acc2[i][ot] = (f4){0.f, 0.f, 0.f, 0.f};

#pragma unroll
    for (int kt = 0; kt < 2; ++kt) {
        const int bc2 = kt * 8 + agrp * 2;
#pragma unroll
        for (int i = 0; i < 4; ++i) {
            const uint2 rA = abuf[wid][(arow * 4 + i) * 16 + (bc2 ^ arow)];
            const uint2 rB = abuf[wid][(arow * 4 + i) * 16 + ((bc2 + 1) ^ arow)];
            int4 ti = make_int4((int)rA.x, (int)rA.y, (int)rB.x, (int)rB.y);
            bf8 bfr = __builtin_bit_cast(bf8, ti);
#pragma unroll
            for (int ot = 0; ot < 4; ++ot)
                acc2[i][ot] = __builtin_amdgcn_mfma_f32_16x16x32_bf16(afr2[ot][kt], bfr, acc2[i][ot], 0, 0, 0);
        }
    }

#pragma unroll
    for (int ot = 0; ot < 4; ++ot) {
#pragma unroll
        for (int r = 0; r < 4; ++r) {
            const int o = ot * 16 + agrp * 4 + r;
            const float bs = b2v[o];
            ushort4 vv4 = *(const ushort4*)&xv[(long long)o * NP + p0];
            float h0 = tanhf((acc2[0][ot][r] + bs) * 0.25f) * bf2f(vv4.x);
            float h1 = tanhf((acc2[1][ot][r] + bs) * 0.25f) * bf2f(vv4.y);
            float h2 = tanhf((acc2[2][ot][r] + bs) * 0.25f) * bf2f(vv4.z);
            float h3 = tanhf((acc2[3][ot][r] + bs) * 0.25f) * bf2f(vv4.w);
            *(uint2*)&hi[((long long)b * 128 + o) * NP + p0] =
                make_uint2(pack_bf2(h0, h1), pack_bf2(h2, h3));
        }
    }
}

// ---------------------------------------------------------------------------
// depthwise 5x5, pad 2 — LDS-staged; bf16 in/out.  (unchanged)
// ---------------------------------------------------------------------------
__global__ __launch_bounds__(256) void k_dwconv5_lds(
    const unsigned short* __restrict__ in, const float* __restrict__ w,
    const float* __restrict__ bias, unsigned short* __restrict__ out, int ch_total)
{
    __shared__ __align__(16) float img[NP];
    const int tid = threadIdx.x;
    const int ch  = blockIdx.x;
    const int b   = blockIdx.y;
    const unsigned short* ip = in + ((long long)b * ch_total + ch) * NP;

#pragma unroll
    for (int j = 0; j < 9; ++j) {
        const uint2 rr = ((const uint2*)ip)[tid + 256 * j];
        float4 f;
        f.x = bflo(rr.x); f.y = bfhi(rr.x);
        f.z = bflo(rr.y); f.w = bfhi(rr.y);
        ((float4*)img)[tid + 256 * j] = f;
    }
    __syncthreads();

    const float* wp = w + ch * 25;
    float wr[25];
#pragma unroll
    for (int i = 0; i < 25; ++i) wr[i] = wp[i];
    const float bs = bias[ch];

    unsigned short* op = out + ((long long)b * ch_total + ch) * NP;

#pragma unroll
    for (int j = 0; j < 9; ++j) {
        const int q  = tid + 256 * j;
        const int y  = q / 24;
        const int x4 = (q - y * 24) * 4;
        float o0 = bs, o1 = bs, o2 = bs, o3 = bs;
#pragma unroll
        for (int ky = 0; ky < 5; ++ky) {
            const int yy = y + ky - 2;
            if (yy < 0 || yy >= HH) continue;
            const float* row = &img[yy * WW + x4];
            float4 mid = *(const float4*)row;
            float4 lf  = (x4 >= 4)      ? *(const float4*)(row - 4)
                                        : make_float4(0.f, 0.f, 0.f, 0.f);
            float4 rt  = (x4 + 4 < WW)  ? *(const float4*)(row + 4)
                                        : make_float4(0.f, 0.f, 0.f, 0.f);
            const float f0 = lf.z,  f1 = lf.w;
            const float f2 = mid.x, f3 = mid.y, f4v = mid.z, f5 = mid.w;
            const float f6 = rt.x,  f7 = rt.y;
            const float w0 = wr[ky * 5 + 0], w1 = wr[ky * 5 + 1],
                        w2 = wr[ky * 5 + 2], w3 = wr[ky * 5 + 3],
                        w4 = wr[ky * 5 + 4];
            o0 = fmaf(w0, f0, o0); o0 = fmaf(w1, f1, o0); o0 = fmaf(w2, f2, o0);
            o0 = fmaf(w3, f3, o0); o0 = fmaf(w4, f4v, o0);
            o1 = fmaf(w0, f1, o1); o1 = fmaf(w1, f2, o1); o1 = fmaf(w2, f3, o1);
            o1 = fmaf(w3, f4v, o1); o1 = fmaf(w4, f5, o1);
            o2 = fmaf(w0, f2, o2); o2 = fmaf(w1, f3, o2); o2 = fmaf(w2, f4v, o2);
            o2 = fmaf(w3, f5, o2); o2 = fmaf(w4, f6, o2);
            o3 = fmaf(w0, f3, o3); o3 = fmaf(w1, f4v, o3); o3 = fmaf(w2, f5, o3);
            o3 = fmaf(w3, f6, o3); o3 = fmaf(w4, f7, o3);
        }
        *(uint2*)&op[y * WW + x4] = make_uint2(pack_bf2(o0, o1), pack_bf2(o2, o3));
    }
}

// ---------------------------------------------------------------------------
// 4x4 average pool  (unchanged, f32)
// ---------------------------------------------------------------------------
__global__ __launch_bounds__(256) void k_avgpool4(
    const float* __restrict__ in, float* __restrict__ out)
{
    int idx = blockIdx.x * 256 + threadIdx.x;
    int total = NB * 128 * NPK;
    if (idx >= total) return;
    int pw = idx % 24;
    int t  = idx / 24;
    int ph = t % 24;  t /= 24;
    int c  = t % 128;
    int b  = t / 128;
    const float* ip = in + ((long long)b * 128 + c) * NP + (ph * 4) * WW + pw * 4;
    float s = 0.f;
#pragma unroll
    for (int i = 0; i < 4; ++i)
#pragma unroll
        for (int j = 0; j < 4; ++j) s += ip[i * WW + j];
    out[idx] = s * (1.0f / 16.0f);
}

// ---------------------------------------------------------------------------
// MFMA flash-attention v5: r13 inner loop, but K/V staged in TWO 288-key
// halves -> LDS 34KB -> 4 blocks/CU (was 3), 1024 resident blocks (1.125
// rounds vs 1.5).  exp2f (Q pre-scaled by 0.25*log2e), s_setprio around
// the compute body.  4 q-subtiles/wave, E single-buffered.
// ---------------------------------------------------------------------------
__global__ __launch_bounds__(256) void k_attn_mfma(
    const unsigned short* __restrict__ q,  // bf16 (B,64,NP), pre-scaled 0.25*log2e
    const float* __restrict__ kv,          // f32 (B,128,NPK)
    unsigned short* __restrict__ hilo)     // bf16 (B,128,NP), lo at ch 64..127
{
    __shared__ __align__(16) int4  klds4[18 * 32];   // 9KB  (half: 288 keys)
    __shared__ __align__(16) int4  vlds4[9 * 64];    // 9KB  (half: 288 keys)
    __shared__ __align__(16) uint2 elds2[4 * 512];   // 16KB

    const int tid  = threadIdx.x;
    const int lane = tid & 63, wid = tid >> 6;
    const int g    = lane >> 4, qi = lane & 15;
    const int bh   = blockIdx.y, b = bh >> 2, h = bh & 3;

    const float* kbase = kv + ((long long)b * 128 + h * 16) * NPK;
    const float* vbase = kv + ((long long)b * 128 + 64 + h * 16) * NPK;

    const int q0 = (blockIdx.x * 4 + wid) * 64;
    const unsigned short* qcol = q + ((long long)b * 64 + h * 16) * NP + q0 + qi;
    int4 qv[4] = { make_int4(0,0,0,0), make_int4(0,0,0,0),
                   make_int4(0,0,0,0), make_int4(0,0,0,0) };
    if (g < 2) {
#pragma unroll
        for (int s = 0; s < 4; ++s) {
            const unsigned short* qp = qcol + s * 16 + (long long)(g * 8) * NP;
            qv[s].x = (int)((unsigned)qp[0]        | ((unsigned)qp[(long long)NP] << 16));
            qv[s].y = (int)((unsigned)qp[2ll * NP] | ((unsigned)qp[3ll * NP]      << 16));
            qv[s].z = (int)((unsigned)qp[4ll * NP] | ((unsigned)qp[5ll * NP]      << 16));
            qv[s].w = (int)((unsigned)qp[6ll * NP] | ((unsigned)qp[7ll * NP]      << 16));
        }
    }

    f4 accp[4] = { (f4){0.f,0.f,0.f,0.f}, (f4){0.f,0.f,0.f,0.f},
                   (f4){0.f,0.f,0.f,0.f}, (f4){0.f,0.f,0.f,0.f} };
    float den[4] = { 0.f, 0.f, 0.f, 0.f };
    const int wb = wid * 512;

    for (int half = 0; half < 2; ++half) {
        __syncthreads();   // previous half's compute done before restaging
        const int koff = half * 288;
        // stage K half: 288 keys x 2 d-groups
        for (int i = tid; i < 576; i += 256) {
            const int key = i >> 1, dg = i & 1;
            const float* kp = kbase + (long long)(dg * 8) * NPK + koff + key;
            int4 t;
            t.x = (int)pack_bf2(kp[0],       kp[NPK]);
            t.y = (int)pack_bf2(kp[2 * NPK], kp[3 * NPK]);
            t.z = (int)pack_bf2(kp[4 * NPK], kp[5 * NPK]);
            t.w = (int)pack_bf2(kp[6 * NPK], kp[7 * NPK]);
            klds4[(key >> 4) * 32 + dg * 16 + (key & 15)] = t;
        }
        // stage V^T half: 9 tiles of 32 keys
        for (int i = tid; i < 576; i += 256) {
            const int t8 = i >> 6, l = i & 63;
            const float* vp = vbase + (long long)(l & 15) * NPK + koff + t8 * 32 + (l >> 4) * 8;
            float4 a = *(const float4*)vp;
            float4 c = *(const float4*)(vp + 4);
            int4 tt;
            tt.x = (int)pack_bf2(a.x, a.y);
            tt.y = (int)pack_bf2(a.z, a.w);
            tt.z = (int)pack_bf2(c.x, c.y);
            tt.w = (int)pack_bf2(c.z, c.w);
            vlds4[i] = tt;
        }
        __syncthreads();

        for (int k2 = 0; k2 < 9; ++k2) {
            __builtin_amdgcn_s_setprio(1);
#pragma unroll
            for (int tp = 0; tp < 2; ++tp) {
                int4 kf = klds4[(k2 * 2 + tp) * 32 + (lane & 31)];
                if (lane >= 32) kf = make_int4(0, 0, 0, 0);   // d-padding rows
                const bf8 ka = __builtin_bit_cast(bf8, kf);
#pragma unroll
                for (int s = 0; s < 4; ++s) {
                    f4 sa = __builtin_amdgcn_mfma_f32_16x16x32_bf16(
                        ka, __builtin_bit_cast(bf8, qv[s]), (f4){0.f, 0.f, 0.f, 0.f}, 0, 0, 0);
                    const float e0 = exp2f(sa[0]), e1 = exp2f(sa[1]);
                    const float e2 = exp2f(sa[2]), e3 = exp2f(sa[3]);
                    den[s] += (e0 + e1) + (e2 + e3);
                    elds2[wb + s * 128 + tp * 64 + g * 16 + qi] =
                        make_uint2(pack_bf2(e0, e1), pack_bf2(e2, e3));
                }
            }
            const bf8 va = __builtin_bit_cast(bf8, vlds4[k2 * 64 + lane]);
#pragma unroll
            for (int s = 0; s < 4; ++s) {
                const int base = wb + s * 128 + (g >> 1) * 64 + (g & 1) * 32 + qi;
                const uint2 r0 = elds2[base];
                const uint2 r1 = elds2[base + 16];
                int4 ti = make_int4((int)r0.x, (int)r0.y, (int)r1.x, (int)r1.y);
                accp[s] = __builtin_amdgcn_mfma_f32_16x16x32_bf16(
                    va, __builtin_bit_cast(bf8, ti), accp[s], 0, 0, 0);
            }
            __builtin_amdgcn_s_setprio(0);
        }
    }

#pragma unroll
    for (int s = 0; s < 4; ++s) {
        float d0 = den[s];
        d0 += __shfl_xor(d0, 16, 64);
        d0 += __shfl_xor(d0, 32, 64);
        const float inv = 1.0f / d0;
        unsigned short* op = hilo + ((long long)b * 128 + 64 + h * 16 + g * 4) * NP + q0 + s * 16 + qi;
#pragma unroll
        for (int r = 0; r < 4; ++r)
            op[(long long)r * NP] = f2bfu(accp[s][r] * inv);
    }
}

// ---------------------------------------------------------------------------
extern "C" void kernel_launch(void* const* d_in, const int* in_sizes, int n_in,
                              void* d_out, int out_size, void* d_ws, size_t ws_size,
                              hipStream_t stream)
{
    const float* x      = (const float*)d_in[0];
    const float* qkv_w  = (const float*)d_in[1];
    const float* qkv_b  = (const float*)d_in[2];
    const float* dw_w   = (const float*)d_in[3];
    const float* dw_b   = (const float*)d_in[4];
    const float* am_w1  = (const float*)d_in[5];
    const float* am_b1  = (const float*)d_in[6];
    const float* am_w2  = (const float*)d_in[7];
    const float* am_b2  = (const float*)d_in[8];
    const float* gq_w   = (const float*)d_in[9];
    const float* gq_b   = (const float*)d_in[10];
    const float* gkv_w  = (const float*)d_in[11];
    const float* gkv_b  = (const float*)d_in[12];
    const float* proj_w = (const float*)d_in[13];
    const float* proj_b = (const float*)d_in[14];
    float* out = (float*)d_out;
    char* wsb = (char*)d_ws;

    unsigned short* t_qkv  = (unsigned short*)wsb;               // bf16 (8,192,9216)
    unsigned short* t_hilo = (unsigned short*)wsb;               // bf16 (8,128,9216) (reuse)
    unsigned short* t_dw   = (unsigned short*)(wsb + 28311552);  // bf16 (8,192,9216)
    unsigned short* t_gq   = (unsigned short*)(wsb + 56623104);  // bf16 (8,64,9216)
    float*          t_pool = (float*)(wsb + 66060288);           // f32 (8,128,576)
    float*          t_gkv  = (float*)(wsb + 68419584);           // f32 (8,128,576)

    // 1. qkv (bf16) + gq (bf16, *0.25*log2e) from one LDS-staged read of x
    k_qkvgq<<<dim3(144, 1, NB), 256, 0, stream>>>(
        x, qkv_w, qkv_b, gq_w, gq_b, t_qkv, t_gq);
    // 2. depthwise 5x5 (bf16 in -> bf16 out)
    k_dwconv5_lds<<<dim3(192, NB), 256, 0, stream>>>(t_qkv, dw_w, dw_b, t_dw, 192);
    // 3. pooled = avgpool4(x)
    k_avgpool4<<<dim3((NB*128*NPK + 255)/256), 256, 0, stream>>>(x, t_pool);
    // 4. gkv = conv1x1(pooled)  f32 out
    k_mfma_conv<128,4,0,0><<<dim3(3,2,NB), 256, 0, stream>>>(
        t_pool, gkv_w, gkv_b, t_gkv, NPK, (long long)128 * NPK, 128, 1.0f);
    // 5. fused am -> hilo ch 0..63 (bf16)
    k_am_fused<<<dim3(36,1,NB), 256, 0, stream>>>(
        t_dw, am_w1, am_b1, am_w2, am_b2, t_hilo);
    // 6. attention (half-staged K/V, 4 blk/CU) -> hilo ch 64..127 (bf16)
    k_attn_mfma<<<dim3(36, 32), 256, 0, stream>>>(t_gq, t_gkv, t_hilo);
    // 7. out = conv1x1(hilo bf16, proj_w)  f32 out
    k_mfma_conv<128,4,1,0><<<dim3(36,2,NB), 256, 0, stream>>>(
        t_hilo, proj_w, proj_b, out, NP, (long long)128 * NP, 128, 1.0f);
}

// Round 15
// 187.222 us; speedup vs baseline: 1.0033x; 1.0033x over previous
//
#include <hip/hip_runtime.h>
#include <hip/hip_bf16.h>
#include <hip/hip_fp16.h>
#include <cstdint>

static constexpr int NB  = 8;
static constexpr int HH  = 96;
static constexpr int WW  = 96;
static constexpr int NP  = 9216;   // 96*96
static constexpr int NPK = 576;    // 24*24

using bf8 = __attribute__((ext_vector_type(8))) short;
using f4  = __attribute__((ext_vector_type(4))) float;

__device__ __forceinline__ unsigned pack_bf2(float a, float b) {
    __hip_bfloat162 h = __float22bfloat162_rn(make_float2(a, b));
    unsigned u; __builtin_memcpy(&u, &h, 4);
    return u;
}
__device__ __forceinline__ unsigned short f2bfu(float f) {
    __hip_bfloat16 h = __float2bfloat16(f);
    unsigned short u; __builtin_memcpy(&u, &h, 2);
    return u;
}
__device__ __forceinline__ float bf2f(unsigned short u) {
    unsigned v = (unsigned)u << 16;
    float f; __builtin_memcpy(&f, &v, 4);
    return f;
}
__device__ __forceinline__ float bflo(unsigned p) {
    unsigned v = p << 16; float f; __builtin_memcpy(&f, &v, 4); return f;
}
__device__ __forceinline__ float bfhi(unsigned p) {
    unsigned v = p & 0xffff0000u; float f; __builtin_memcpy(&f, &v, 4); return f;
}

// ---------------------------------------------------------------------------
// Fused qkv+gq conv1x1 with LDS-staged x. (r12; gq scale = 0.25*log2e, r14-verified)
// ---------------------------------------------------------------------------
__global__ __launch_bounds__(256) void k_qkvgq(
    const float* __restrict__ x,
    const float* __restrict__ qkv_w, const float* __restrict__ qkv_b,
    const float* __restrict__ gq_w,  const float* __restrict__ gq_b,
    unsigned short* __restrict__ qkv_out,   // bf16 (B,192,NP)
    unsigned short* __restrict__ gq_out)    // bf16 (B,64,NP), pre-scaled 0.25*log2e
{
    __shared__ __align__(16) unsigned xl[64 * 64];   // 16KB
    const int tid  = threadIdx.x;
    const int lane = tid & 63, wid = tid >> 6;
    const int quad = blockIdx.x, b = blockIdx.z;
    const int arow = lane & 15, agrp = lane >> 4;

    const float* xb = x + (long long)b * 128 * NP + quad * 64;

#pragma unroll
    for (int it = 0; it < 4; ++it) {
        const int task = tid + 256 * it;
        const int cp = task >> 4, pq = task & 15;
        float4 a = *(const float4*)&xb[(long long)(2 * cp) * NP + pq * 4];
        float4 c = *(const float4*)&xb[(long long)(2 * cp + 1) * NP + pq * 4];
        const int cps = cp ^ ((pq & 7) << 2);
        xl[(pq * 4 + 0) * 64 + cps] = pack_bf2(a.x, c.x);
        xl[(pq * 4 + 1) * 64 + cps] = pack_bf2(a.y, c.y);
        xl[(pq * 4 + 2) * 64 + cps] = pack_bf2(a.z, c.z);
        xl[(pq * 4 + 3) * 64 + cps] = pack_bf2(a.w, c.w);
    }
    __syncthreads();

    uint4 breg[4][4];
#pragma unroll
    for (int kt = 0; kt < 4; ++kt)
#pragma unroll
        for (int i = 0; i < 4; ++i) {
            const int px = arow * 4 + i;
            const int cp = (kt * 16 + agrp * 4) ^ ((arow & 7) << 2);
            breg[kt][i] = *(const uint4*)&xl[px * 64 + cp];
        }

    for (int gi = 0; gi < 4; ++gi) {
        const int grp = wid + gi * 4;
        const bool isgq = grp >= 12;
        const float* wsrc = isgq ? gq_w : qkv_w;
        const float* bsrc = isgq ? gq_b : qkv_b;
        const float wsc = isgq ? 0.36067376022224085f : 1.0f;  // 0.25*log2(e)
        const int och = (isgq ? grp - 12 : grp) * 16;

        bf8 afr[4];
#pragma unroll
        for (int kt = 0; kt < 4; ++kt) {
            const float* wp = wsrc + (long long)(och + arow) * 128 + kt * 32 + agrp * 8;
            int4 t;
            t.x = (int)pack_bf2(wp[0] * wsc, wp[1] * wsc);
            t.y = (int)pack_bf2(wp[2] * wsc, wp[3] * wsc);
            t.z = (int)pack_bf2(wp[4] * wsc, wp[5] * wsc);
            t.w = (int)pack_bf2(wp[6] * wsc, wp[7] * wsc);
            afr[kt] = __builtin_bit_cast(bf8, t);
        }

        f4 acc[4];
#pragma unroll
        for (int i = 0; i < 4; ++i) acc[i] = (f4){0.f, 0.f, 0.f, 0.f};
#pragma unroll
        for (int kt = 0; kt < 4; ++kt)
#pragma unroll
            for (int i = 0; i < 4; ++i)
                acc[i] = __builtin_amdgcn_mfma_f32_16x16x32_bf16(
                    afr[kt], __builtin_bit_cast(bf8, breg[kt][i]), acc[i], 0, 0, 0);

        unsigned short* ob = isgq ? gq_out : qkv_out;
        const int ostride = isgq ? 64 : 192;
#pragma unroll
        for (int r = 0; r < 4; ++r) {
            const int o = och + agrp * 4 + r;
            const float bs = bsrc[o] * wsc;
            const float v0 = acc[0][r] + bs, v1 = acc[1][r] + bs;
            const float v2 = acc[2][r] + bs, v3 = acc[3][r] + bs;
            *(uint2*)&ob[((long long)b * ostride + o) * NP + quad * 64 + arow * 4] =
                make_uint2(pack_bf2(v0, v1), pack_bf2(v2, v3));
        }
    }
}

// ---------------------------------------------------------------------------
// MFMA conv1x1 (generic; gkv f32->f32 and proj bf16->f32).  (unchanged)
// ---------------------------------------------------------------------------
template<int C, int OT, int INBF, int OUTBF>
__global__ __launch_bounds__(256) void k_mfma_conv(
    const void* __restrict__ in0v, const float* __restrict__ w,
    const float* __restrict__ bias, void* __restrict__ outv,
    int np, long long ibs, int storeO, float wscale)
{
    constexpr int KT = C / 32;
    const int tid  = threadIdx.x;
    const int lane = tid & 63, wid = tid >> 6;
    const int b    = blockIdx.z;
    const int obq  = blockIdx.y * (OT * 16);
    const int arow = lane & 15, agrp = lane >> 4;
    const int nquad = np >> 6;

    bf8 afr[OT][KT];
#pragma unroll
    for (int ot = 0; ot < OT; ++ot)
#pragma unroll
        for (int kt = 0; kt < KT; ++kt) {
            const float* wp = w + (long long)(obq + ot * 16 + arow) * C + kt * 32 + agrp * 8;
            int4 t;
            t.x = (int)pack_bf2(wp[0] * wscale, wp[1] * wscale);
            t.y = (int)pack_bf2(wp[2] * wscale, wp[3] * wscale);
            t.z = (int)pack_bf2(wp[4] * wscale, wp[5] * wscale);
            t.w = (int)pack_bf2(wp[6] * wscale, wp[7] * wscale);
            afr[ot][kt] = __builtin_bit_cast(bf8, t);
        }

    const float*          x0f = (const float*)in0v          + (long long)b * (INBF ? 0 : ibs);
    const unsigned short* x0h = (const unsigned short*)in0v + (long long)b * (INBF ? ibs : 0);

    const int quad = blockIdx.x * 4 + wid;
    if (quad >= nquad) return;
    const int p0 = quad * 64 + arow * 4;

    f4 acc[4][OT];
#pragma unroll
    for (int i = 0; i < 4; ++i)
#pragma unroll
        for (int ot = 0; ot < OT; ++ot) acc[i][ot] = (f4){0.f, 0.f, 0.f, 0.f};

#pragma unroll
    for (int kt = 0; kt < KT; ++kt) {
        const long long cbase = kt * 32 + agrp * 8;
        int uu[4][4];
#pragma unroll
        for (int jj = 0; jj < 4; ++jj) {
            if (INBF == 0) {
                float4 a0 = *(const float4*)&x0f[(cbase + 2 * jj) * np + p0];
                float4 a1 = *(const float4*)&x0f[(cbase + 2 * jj + 1) * np + p0];
                uu[0][jj] = (int)pack_bf2(a0.x, a1.x);
                uu[1][jj] = (int)pack_bf2(a0.y, a1.y);
                uu[2][jj] = (int)pack_bf2(a0.z, a1.z);
                uu[3][jj] = (int)pack_bf2(a0.w, a1.w);
            } else {
                ushort4 a0 = *(const ushort4*)&x0h[(cbase + 2 * jj) * np + p0];
                ushort4 a1 = *(const ushort4*)&x0h[(cbase + 2 * jj + 1) * np + p0];
                uu[0][jj] = (int)((unsigned)a0.x | ((unsigned)a1.x << 16));
                uu[1][jj] = (int)((unsigned)a0.y | ((unsigned)a1.y << 16));
                uu[2][jj] = (int)((unsigned)a0.z | ((unsigned)a1.z << 16));
                uu[3][jj] = (int)((unsigned)a0.w | ((unsigned)a1.w << 16));
            }
        }
#pragma unroll
        for (int i = 0; i < 4; ++i) {
            int4 ti = {uu[i][0], uu[i][1], uu[i][2], uu[i][3]};
            bf8 bfr = __builtin_bit_cast(bf8, ti);
#pragma unroll
            for (int ot = 0; ot < OT; ++ot)
                acc[i][ot] = __builtin_amdgcn_mfma_f32_16x16x32_bf16(afr[ot][kt], bfr, acc[i][ot], 0, 0, 0);
        }
    }

#pragma unroll
    for (int ot = 0; ot < OT; ++ot) {
#pragma unroll
        for (int r = 0; r < 4; ++r) {
            const int o = obq + ot * 16 + agrp * 4 + r;
            const float bs = bias[o] * wscale;
            float4 v;
            v.x = acc[0][ot][r] + bs;
            v.y = acc[1][ot][r] + bs;
            v.z = acc[2][ot][r] + bs;
            v.w = acc[3][ot][r] + bs;
            const long long idx = ((long long)b * storeO + o) * np + p0;
            if (OUTBF == 0) {
                *(float4*)&((float*)outv)[idx] = v;
            } else {
                *(uint2*)&((unsigned short*)outv)[idx] =
                    make_uint2(pack_bf2(v.x, v.y), pack_bf2(v.z, v.w));
            }
        }
    }
}

// ---------------------------------------------------------------------------
// Fused am1+am2 (bf16 I/O), unchanged.
// ---------------------------------------------------------------------------
__global__ __launch_bounds__(256) void k_am_fused(
    const unsigned short* __restrict__ dw,   // bf16: q +0, k +64NP, v +128NP
    const float* __restrict__ w1, const float* __restrict__ b1v,
    const float* __restrict__ w2, const float* __restrict__ b2v,
    unsigned short* __restrict__ hi)         // bf16 hilo ch 0..63
{
    __shared__ __align__(16) uint2 abuf[4][1024];

    const int tid  = threadIdx.x;
    const int lane = tid & 63, wid = tid >> 6;
    const int b    = blockIdx.z;
    const int arow = lane & 15, agrp = lane >> 4;

    bf8 afr1[4][2], afr2[4][2];
#pragma unroll
    for (int ot = 0; ot < 4; ++ot)
#pragma unroll
        for (int kt = 0; kt < 2; ++kt) {
            const float* wp1 = w1 + (long long)(ot * 16 + arow) * 64 + kt * 32 + agrp * 8;
            const float* wp2 = w2 + (long long)(ot * 16 + arow) * 64 + kt * 32 + agrp * 8;
            int4 t1, t2;
            t1.x = (int)pack_bf2(wp1[0], wp1[1]);  t2.x = (int)pack_bf2(wp2[0], wp2[1]);
            t1.y = (int)pack_bf2(wp1[2], wp1[3]);  t2.y = (int)pack_bf2(wp2[2], wp2[3]);
            t1.z = (int)pack_bf2(wp1[4], wp1[5]);  t2.z = (int)pack_bf2(wp2[4], wp2[5]);
            t1.w = (int)pack_bf2(wp1[6], wp1[7]);  t2.w = (int)pack_bf2(wp2[6], wp2[7]);
            afr1[ot][kt] = __builtin_bit_cast(bf8, t1);
            afr2[ot][kt] = __builtin_bit_cast(bf8, t2);
        }

    const unsigned short* xq = dw + (long long)b * (192ll * NP);
    const unsigned short* xk = xq + 64ll * NP;
    const unsigned short* xv = xq + 128ll * NP;

    const int quad = blockIdx.x * 4 + wid;
    const int p0 = quad * 64 + arow * 4;

    f4 acc1[4][4];
#pragma unroll
    for (int i = 0; i < 4; ++i)
#pragma unroll
        for (int ot = 0; ot < 4; ++ot) acc1[i][ot] = (f4){0.f, 0.f, 0.f, 0.f};

#pragma unroll
    for (int kt = 0; kt < 2; ++kt) {
        const long long cbase = kt * 32 + agrp * 8;
        int uu[4][4];
#pragma unroll
        for (int jj = 0; jj < 4; ++jj) {
            ushort4 a0 = *(const ushort4*)&xq[(cbase + 2 * jj) * NP + p0];
            ushort4 a1 = *(const ushort4*)&xq[(cbase + 2 * jj + 1) * NP + p0];
            ushort4 y0 = *(const ushort4*)&xk[(cbase + 2 * jj) * NP + p0];
            ushort4 y1 = *(const ushort4*)&xk[(cbase + 2 * jj + 1) * NP + p0];
            uu[0][jj] = (int)pack_bf2(bf2f(a0.x) * bf2f(y0.x), bf2f(a1.x) * bf2f(y1.x));
            uu[1][jj] = (int)pack_bf2(bf2f(a0.y) * bf2f(y0.y), bf2f(a1.y) * bf2f(y1.y));
            uu[2][jj] = (int)pack_bf2(bf2f(a0.z) * bf2f(y0.z), bf2f(a1.z) * bf2f(y1.z));
            uu[3][jj] = (int)pack_bf2(bf2f(a0.w) * bf2f(y0.w), bf2f(a1.w) * bf2f(y1.w));
        }
#pragma unroll
        for (int i = 0; i < 4; ++i) {
            int4 ti = {uu[i][0], uu[i][1], uu[i][2], uu[i][3]};
            bf8 bfr = __builtin_bit_cast(bf8, ti);
#pragma unroll
            for (int ot = 0; ot < 4; ++ot)
                acc1[i][ot] = __builtin_amdgcn_mfma_f32_16x16x32_bf16(afr1[ot][kt], bfr, acc1[i][ot], 0, 0, 0);
        }
    }

#pragma unroll
    for (int i = 0; i < 4; ++i)
#pragma unroll
        for (int ot = 0; ot < 4; ++ot) {
            const int ch0 = ot * 16 + agrp * 4;
            float v0 = acc1[i][ot][0] + b1v[ch0 + 0];
            float v1 = acc1[i][ot][1] + b1v[ch0 + 1];
            float v2 = acc1[i][ot][2] + b1v[ch0 + 2];
            float v3 = acc1[i][ot][3] + b1v[ch0 + 3];
            v0 = v0 / (1.f + __expf(-v0));
            v1 = v1 / (1.f + __expf(-v1));
            v2 = v2 / (1.f + __expf(-v2));
            v3 = v3 / (1.f + __expf(-v3));
            const int c2 = ot * 4 + agrp;
            abuf[wid][(arow * 4 + i) * 16 + (c2 ^ arow)] =
                make_uint2(pack_bf2(v0, v1), pack_bf2(v2, v3));
        }

    f4 acc2[4][4];
#pragma unroll
    for (int i = 0; i < 4; ++i)
#pragma unroll
        for (int ot = 0; ot < 4; ++ot) acc2[i][ot] = (f4){0.f, 0.f, 0.f, 0.f};

#pragma unroll
    for (int kt = 0; kt < 2; ++kt) {
        const int bc2 = kt * 8 + agrp * 2;
#pragma unroll
        for (int i = 0; i < 4; ++i) {
            const uint2 rA = abuf[wid][(arow * 4 + i) * 16 + (bc2 ^ arow)];
            const uint2 rB = abuf[wid][(arow * 4 + i) * 16 + ((bc2 + 1) ^ arow)];
            int4 ti = make_int4((int)rA.x, (int)rA.y, (int)rB.x, (int)rB.y);
            bf8 bfr = __builtin_bit_cast(bf8, ti);
#pragma unroll
            for (int ot = 0; ot < 4; ++ot)
                acc2[i][ot] = __builtin_amdgcn_mfma_f32_16x16x32_bf16(afr2[ot][kt], bfr, acc2[i][ot], 0, 0, 0);
        }
    }

#pragma unroll
    for (int ot = 0; ot < 4; ++ot) {
#pragma unroll
        for (int r = 0; r < 4; ++r) {
            const int o = ot * 16 + agrp * 4 + r;
            const float bs = b2v[o];
            ushort4 vv4 = *(const ushort4*)&xv[(long long)o * NP + p0];
            float h0 = tanhf((acc2[0][ot][r] + bs) * 0.25f) * bf2f(vv4.x);
            float h1 = tanhf((acc2[1][ot][r] + bs) * 0.25f) * bf2f(vv4.y);
            float h2 = tanhf((acc2[2][ot][r] + bs) * 0.25f) * bf2f(vv4.z);
            float h3 = tanhf((acc2[3][ot][r] + bs) * 0.25f) * bf2f(vv4.w);
            *(uint2*)&hi[((long long)b * 128 + o) * NP + p0] =
                make_uint2(pack_bf2(h0, h1), pack_bf2(h2, h3));
        }
    }
}

// ---------------------------------------------------------------------------
// depthwise 5x5, pad 2 — LDS-staged; bf16 in/out.  (unchanged)
// ---------------------------------------------------------------------------
__global__ __launch_bounds__(256) void k_dwconv5_lds(
    const unsigned short* __restrict__ in, const float* __restrict__ w,
    const float* __restrict__ bias, unsigned short* __restrict__ out, int ch_total)
{
    __shared__ __align__(16) float img[NP];
    const int tid = threadIdx.x;
    const int ch  = blockIdx.x;
    const int b   = blockIdx.y;
    const unsigned short* ip = in + ((long long)b * ch_total + ch) * NP;

#pragma unroll
    for (int j = 0; j < 9; ++j) {
        const uint2 rr = ((const uint2*)ip)[tid + 256 * j];
        float4 f;
        f.x = bflo(rr.x); f.y = bfhi(rr.x);
        f.z = bflo(rr.y); f.w = bfhi(rr.y);
        ((float4*)img)[tid + 256 * j] = f;
    }
    __syncthreads();

    const float* wp = w + ch * 25;
    float wr[25];
#pragma unroll
    for (int i = 0; i < 25; ++i) wr[i] = wp[i];
    const float bs = bias[ch];

    unsigned short* op = out + ((long long)b * ch_total + ch) * NP;

#pragma unroll
    for (int j = 0; j < 9; ++j) {
        const int q  = tid + 256 * j;
        const int y  = q / 24;
        const int x4 = (q - y * 24) * 4;
        float o0 = bs, o1 = bs, o2 = bs, o3 = bs;
#pragma unroll
        for (int ky = 0; ky < 5; ++ky) {
            const int yy = y + ky - 2;
            if (yy < 0 || yy >= HH) continue;
            const float* row = &img[yy * WW + x4];
            float4 mid = *(const float4*)row;
            float4 lf  = (x4 >= 4)      ? *(const float4*)(row - 4)
                                        : make_float4(0.f, 0.f, 0.f, 0.f);
            float4 rt  = (x4 + 4 < WW)  ? *(const float4*)(row + 4)
                                        : make_float4(0.f, 0.f, 0.f, 0.f);
            const float f0 = lf.z,  f1 = lf.w;
            const float f2 = mid.x, f3 = mid.y, f4v = mid.z, f5 = mid.w;
            const float f6 = rt.x,  f7 = rt.y;
            const float w0 = wr[ky * 5 + 0], w1 = wr[ky * 5 + 1],
                        w2 = wr[ky * 5 + 2], w3 = wr[ky * 5 + 3],
                        w4 = wr[ky * 5 + 4];
            o0 = fmaf(w0, f0, o0); o0 = fmaf(w1, f1, o0); o0 = fmaf(w2, f2, o0);
            o0 = fmaf(w3, f3, o0); o0 = fmaf(w4, f4v, o0);
            o1 = fmaf(w0, f1, o1); o1 = fmaf(w1, f2, o1); o1 = fmaf(w2, f3, o1);
            o1 = fmaf(w3, f4v, o1); o1 = fmaf(w4, f5, o1);
            o2 = fmaf(w0, f2, o2); o2 = fmaf(w1, f3, o2); o2 = fmaf(w2, f4v, o2);
            o2 = fmaf(w3, f5, o2); o2 = fmaf(w4, f6, o2);
            o3 = fmaf(w0, f3, o3); o3 = fmaf(w1, f4v, o3); o3 = fmaf(w2, f5, o3);
            o3 = fmaf(w3, f6, o3); o3 = fmaf(w4, f7, o3);
        }
        *(uint2*)&op[y * WW + x4] = make_uint2(pack_bf2(o0, o1), pack_bf2(o2, o3));
    }
}

// ---------------------------------------------------------------------------
// 4x4 average pool — float4 loads (4 vector loads/thread vs 16 scalar).
// ---------------------------------------------------------------------------
__global__ __launch_bounds__(256) void k_avgpool4(
    const float* __restrict__ in, float* __restrict__ out)
{
    int idx = blockIdx.x * 256 + threadIdx.x;
    int total = NB * 128 * NPK;
    if (idx >= total) return;
    int pw = idx % 24;
    int t  = idx / 24;
    int ph = t % 24;  t /= 24;
    int c  = t % 128;
    int b  = t / 128;
    const float* ip = in + ((long long)b * 128 + c) * NP + (ph * 4) * WW + pw * 4;
    float4 r0 = *(const float4*)(ip);
    float4 r1 = *(const float4*)(ip + WW);
    float4 r2 = *(const float4*)(ip + 2 * WW);
    float4 r3 = *(const float4*)(ip + 3 * WW);
    float s = ((r0.x + r0.y) + (r0.z + r0.w)) + ((r1.x + r1.y) + (r1.z + r1.w))
            + ((r2.x + r2.y) + (r2.z + r2.w)) + ((r3.x + r3.y) + (r3.z + r3.w));
    out[idx] = s * (1.0f / 16.0f);
}

// ---------------------------------------------------------------------------
// MFMA flash-attention — r12 structure (grid 72x32, 2 q-subtiles, E dbuf)
// + exp2 (Q pre-scaled 0.25*log2e, r14-verified) + den via ones-MFMA
// (r8-verified; kills den adds + final shfls) + s_setprio (m191).
// LDS: K 18K + z 0.5K + V 18K + E 16K = 52.5KB; 3 blk/CU; grid 2304 = 3 rounds.
// ---------------------------------------------------------------------------
__global__ __launch_bounds__(256) void k_attn_mfma(
    const unsigned short* __restrict__ q,  // bf16 (B,64,NP), pre-scaled 0.25*log2e
    const float* __restrict__ kv,          // f32 (B,128,NPK)
    unsigned short* __restrict__ hilo)     // bf16 (B,128,NP), lo at ch 64..127
{
    __shared__ __align__(16) int4  klds4[36 * 32];
    __shared__ __align__(16) int4  zlds4[32];
    __shared__ __align__(16) int4  vlds4[18 * 64];
    __shared__ __align__(16) uint2 elds2[2][4 * 256];

    const int tid  = threadIdx.x;
    const int lane = tid & 63, wid = tid >> 6;
    const int g    = lane >> 4, qi = lane & 15;
    const int bh   = blockIdx.y, b = bh >> 2, h = bh & 3;

    const float* kbase = kv + ((long long)b * 128 + h * 16) * NPK;
    const float* vbase = kv + ((long long)b * 128 + 64 + h * 16) * NPK;

    for (int i = tid; i < 1152; i += 256) {
        const int key = i >> 1, dg = i & 1;
        const float* kp = kbase + (long long)(dg * 8) * NPK + key;
        int4 t;
        t.x = (int)pack_bf2(kp[0],       kp[NPK]);
        t.y = (int)pack_bf2(kp[2 * NPK], kp[3 * NPK]);
        t.z = (int)pack_bf2(kp[4 * NPK], kp[5 * NPK]);
        t.w = (int)pack_bf2(kp[6 * NPK], kp[7 * NPK]);
        klds4[(key >> 4) * 32 + dg * 16 + (key & 15)] = t;
    }
    for (int i = tid; i < 1152; i += 256) {
        const int t = i >> 6, l = i & 63;
        const float* vp = vbase + (long long)(l & 15) * NPK + t * 32 + (l >> 4) * 8;
        float4 a = *(const float4*)vp;
        float4 c = *(const float4*)(vp + 4);
        int4 tt;
        tt.x = (int)pack_bf2(a.x, a.y);
        tt.y = (int)pack_bf2(a.z, a.w);
        tt.z = (int)pack_bf2(c.x, c.y);
        tt.w = (int)pack_bf2(c.z, c.w);
        vlds4[i] = tt;
    }
    if (tid < 32) zlds4[tid] = make_int4(0, 0, 0, 0);
    __syncthreads();

    const int q0 = (blockIdx.x * 4 + wid) * 32;
    const unsigned short* qcol = q + ((long long)b * 64 + h * 16) * NP + q0 + qi;
    int4 qv[2] = { make_int4(0, 0, 0, 0), make_int4(0, 0, 0, 0) };
    if (g < 2) {
#pragma unroll
        for (int s = 0; s < 2; ++s) {
            const unsigned short* qp = qcol + s * 16 + (long long)(g * 8) * NP;
            qv[s].x = (int)((unsigned)qp[0]          | ((unsigned)qp[(long long)NP]     << 16));
            qv[s].y = (int)((unsigned)qp[2ll * NP]   | ((unsigned)qp[3ll * NP]          << 16));
            qv[s].z = (int)((unsigned)qp[4ll * NP]   | ((unsigned)qp[5ll * NP]          << 16));
            qv[s].w = (int)((unsigned)qp[6ll * NP]   | ((unsigned)qp[7ll * NP]          << 16));
        }
    }

    const bf8 ones = { (short)0x3F80, (short)0x3F80, (short)0x3F80, (short)0x3F80,
                       (short)0x3F80, (short)0x3F80, (short)0x3F80, (short)0x3F80 };

    f4 accp[2] = { (f4){0.f, 0.f, 0.f, 0.f}, (f4){0.f, 0.f, 0.f, 0.f} };
    f4 dacc[2] = { (f4){0.f, 0.f, 0.f, 0.f}, (f4){0.f, 0.f, 0.f, 0.f} };

    auto QKEXP = [&](int k2, int buf) {
#pragma unroll
        for (int tp = 0; tp < 2; ++tp) {
            const int4 kf = (lane < 32) ? klds4[(k2 * 2 + tp) * 32 + lane]
                                        : zlds4[lane & 31];
            const bf8 ka = __builtin_bit_cast(bf8, kf);
#pragma unroll
            for (int s = 0; s < 2; ++s) {
                f4 sa = __builtin_amdgcn_mfma_f32_16x16x32_bf16(
                    ka, __builtin_bit_cast(bf8, qv[s]), (f4){0.f, 0.f, 0.f, 0.f}, 0, 0, 0);
                elds2[buf][wid * 256 + s * 128 + tp * 64 + g * 16 + qi] =
                    make_uint2(pack_bf2(exp2f(sa[0]), exp2f(sa[1])),
                               pack_bf2(exp2f(sa[2]), exp2f(sa[3])));
            }
        }
    };
    auto PV = [&](int k2, int buf) {
        const bf8 va = __builtin_bit_cast(bf8, vlds4[k2 * 64 + lane]);
#pragma unroll
        for (int s = 0; s < 2; ++s) {
            const int base = wid * 256 + s * 128 + (g >> 1) * 64 + (g & 1) * 32 + qi;
            const uint2 r0 = elds2[buf][base];
            const uint2 r1 = elds2[buf][base + 16];
            int4 ti = make_int4((int)r0.x, (int)r0.y, (int)r1.x, (int)r1.y);
            accp[s] = __builtin_amdgcn_mfma_f32_16x16x32_bf16(
                va, __builtin_bit_cast(bf8, ti), accp[s], 0, 0, 0);
            dacc[s] = __builtin_amdgcn_mfma_f32_16x16x32_bf16(
                ones, __builtin_bit_cast(bf8, ti), dacc[s], 0, 0, 0);
        }
    };

    QKEXP(0, 0);
    for (int k2 = 0; k2 < 17; ++k2) {
        __builtin_amdgcn_s_setprio(1);
        QKEXP(k2 + 1, (k2 + 1) & 1);
        PV(k2, k2 & 1);
        __builtin_amdgcn_s_setprio(0);
    }
    PV(17, 1);

#pragma unroll
    for (int s = 0; s < 2; ++s) {
        const float inv = 1.0f / dacc[s][0];
        unsigned short* op = hilo + ((long long)b * 128 + 64 + h * 16 + g * 4) * NP + q0 + s * 16 + qi;
#pragma unroll
        for (int r = 0; r < 4; ++r)
            op[(long long)r * NP] = f2bfu(accp[s][r] * inv);
    }
}

// ---------------------------------------------------------------------------
extern "C" void kernel_launch(void* const* d_in, const int* in_sizes, int n_in,
                              void* d_out, int out_size, void* d_ws, size_t ws_size,
                              hipStream_t stream)
{
    const float* x      = (const float*)d_in[0];
    const float* qkv_w  = (const float*)d_in[1];
    const float* qkv_b  = (const float*)d_in[2];
    const float* dw_w   = (const float*)d_in[3];
    const float* dw_b   = (const float*)d_in[4];
    const float* am_w1  = (const float*)d_in[5];
    const float* am_b1  = (const float*)d_in[6];
    const float* am_w2  = (const float*)d_in[7];
    const float* am_b2  = (const float*)d_in[8];
    const float* gq_w   = (const float*)d_in[9];
    const float* gq_b   = (const float*)d_in[10];
    const float* gkv_w  = (const float*)d_in[11];
    const float* gkv_b  = (const float*)d_in[12];
    const float* proj_w = (const float*)d_in[13];
    const float* proj_b = (const float*)d_in[14];
    float* out = (float*)d_out;
    char* wsb = (char*)d_ws;

    unsigned short* t_qkv  = (unsigned short*)wsb;               // bf16 (8,192,9216)
    unsigned short* t_hilo = (unsigned short*)wsb;               // bf16 (8,128,9216) (reuse)
    unsigned short* t_dw   = (unsigned short*)(wsb + 28311552);  // bf16 (8,192,9216)
    unsigned short* t_gq   = (unsigned short*)(wsb + 56623104);  // bf16 (8,64,9216)
    float*          t_pool = (float*)(wsb + 66060288);           // f32 (8,128,576)
    float*          t_gkv  = (float*)(wsb + 68419584);           // f32 (8,128,576)

    // 1. qkv (bf16) + gq (bf16, *0.25*log2e) from one LDS-staged read of x
    k_qkvgq<<<dim3(144, 1, NB), 256, 0, stream>>>(
        x, qkv_w, qkv_b, gq_w, gq_b, t_qkv, t_gq);
    // 2. depthwise 5x5 (bf16 in -> bf16 out)
    k_dwconv5_lds<<<dim3(192, NB), 256, 0, stream>>>(t_qkv, dw_w, dw_b, t_dw, 192);
    // 3. pooled = avgpool4(x)  (float4 loads)
    k_avgpool4<<<dim3((NB*128*NPK + 255)/256), 256, 0, stream>>>(x, t_pool);
    // 4. gkv = conv1x1(pooled)  f32 out
    k_mfma_conv<128,4,0,0><<<dim3(3,2,NB), 256, 0, stream>>>(
        t_pool, gkv_w, gkv_b, t_gkv, NPK, (long long)128 * NPK, 128, 1.0f);
    // 5. fused am -> hilo ch 0..63 (bf16)
    k_am_fused<<<dim3(36,1,NB), 256, 0, stream>>>(
        t_dw, am_w1, am_b1, am_w2, am_b2, t_hilo);
    // 6. attention (r12 geometry + exp2/ones-den/setprio) -> hilo ch 64..127
    k_attn_mfma<<<dim3(72, 32), 256, 0, stream>>>(t_gq, t_gkv, t_hilo);
    // 7. out = conv1x1(hilo bf16, proj_w)  f32 out
    k_mfma_conv<128,4,1,0><<<dim3(36,2,NB), 256, 0, stream>>>(
        t_hilo, proj_w, proj_b, out, NP, (long long)128 * NP, 128, 1.0f);
}

// Round 17
// 155.377 us; speedup vs baseline: 1.2090x; 1.2050x over previous
//
#include <hip/hip_runtime.h>
#include <hip/hip_bf16.h>
#include <hip/hip_fp16.h>
#include <cstdint>

static constexpr int NB  = 8;
static constexpr int HH  = 96;
static constexpr int WW  = 96;
static constexpr int NP  = 9216;   // 96*96
static constexpr int NPK = 576;    // 24*24

using bf8 = __attribute__((ext_vector_type(8))) short;
using f4  = __attribute__((ext_vector_type(4))) float;

__device__ __forceinline__ unsigned pack_bf2(float a, float b) {
    __hip_bfloat162 h = __float22bfloat162_rn(make_float2(a, b));
    unsigned u; __builtin_memcpy(&u, &h, 4);
    return u;
}
__device__ __forceinline__ unsigned short f2bfu(float f) {
    __hip_bfloat16 h = __float2bfloat16(f);
    unsigned short u; __builtin_memcpy(&u, &h, 2);
    return u;
}
__device__ __forceinline__ float bf2f(unsigned short u) {
    unsigned v = (unsigned)u << 16;
    float f; __builtin_memcpy(&f, &v, 4);
    return f;
}
__device__ __forceinline__ float bflo(unsigned p) {
    unsigned v = p << 16; float f; __builtin_memcpy(&f, &v, 4); return f;
}
__device__ __forceinline__ float bfhi(unsigned p) {
    unsigned v = p & 0xffff0000u; float f; __builtin_memcpy(&f, &v, 4); return f;
}

// packed-weight segment offsets (uints)
static constexpr int PW_QKV  = 0;       // 192*64
static constexpr int PW_GQ   = 12288;   // 64*64  (scaled 0.25)
static constexpr int PW_GKV  = 16384;   // 128*64
static constexpr int PW_AM1  = 24576;   // 64*32
static constexpr int PW_AM2  = 26624;   // 64*32
static constexpr int PW_PROJ = 28672;   // 128*64
static constexpr int PW_TOTAL= 36864;

// ---------------------------------------------------------------------------
// One-time weight pre-pack: pw[o][j] = pack_bf2(w[o][2j], w[o][2j+1]).
// gq segment scaled by 0.25 (r12 attn semantics).
// ---------------------------------------------------------------------------
__global__ __launch_bounds__(256) void k_packw(
    const float* __restrict__ qkv_w, const float* __restrict__ gq_w,
    const float* __restrict__ gkv_w, const float* __restrict__ am_w1,
    const float* __restrict__ am_w2, const float* __restrict__ proj_w,
    unsigned* __restrict__ pw)
{
    const int idx = blockIdx.x * 256 + threadIdx.x;
    if (idx >= PW_TOTAL) return;
    const float* src; int j2; float sc = 1.0f;
    if (idx < PW_GQ)          { src = qkv_w;  j2 = (idx - PW_QKV) * 2; }
    else if (idx < PW_GKV)    { src = gq_w;   j2 = (idx - PW_GQ) * 2;  sc = 0.25f; }
    else if (idx < PW_AM1)    { src = gkv_w;  j2 = (idx - PW_GKV) * 2; }
    else if (idx < PW_AM2)    { src = am_w1;  j2 = (idx - PW_AM1) * 2; }
    else if (idx < PW_PROJ)   { src = am_w2;  j2 = (idx - PW_AM2) * 2; }
    else                      { src = proj_w; j2 = (idx - PW_PROJ) * 2; }
    pw[idx] = pack_bf2(src[j2] * sc, src[j2 + 1] * sc);
}

// ---------------------------------------------------------------------------
// Fused qkv+gq conv1x1 with LDS-staged x; weights pre-packed.
// ---------------------------------------------------------------------------
__global__ __launch_bounds__(256) void k_qkvgq(
    const float* __restrict__ x, const unsigned* __restrict__ pw,
    const float* __restrict__ qkv_b, const float* __restrict__ gq_b,
    unsigned short* __restrict__ qkv_out,   // bf16 (B,192,NP)
    unsigned short* __restrict__ gq_out)    // bf16 (B,64,NP), pre-scaled 0.25
{
    __shared__ __align__(16) unsigned xl[64 * 64];   // 16KB
    const int tid  = threadIdx.x;
    const int lane = tid & 63, wid = tid >> 6;
    const int quad = blockIdx.x, b = blockIdx.z;
    const int arow = lane & 15, agrp = lane >> 4;

    const float* xb = x + (long long)b * 128 * NP + quad * 64;

#pragma unroll
    for (int it = 0; it < 4; ++it) {
        const int task = tid + 256 * it;
        const int cp = task >> 4, pq = task & 15;
        float4 a = *(const float4*)&xb[(long long)(2 * cp) * NP + pq * 4];
        float4 c = *(const float4*)&xb[(long long)(2 * cp + 1) * NP + pq * 4];
        const int cps = cp ^ ((pq & 7) << 2);
        xl[(pq * 4 + 0) * 64 + cps] = pack_bf2(a.x, c.x);
        xl[(pq * 4 + 1) * 64 + cps] = pack_bf2(a.y, c.y);
        xl[(pq * 4 + 2) * 64 + cps] = pack_bf2(a.z, c.z);
        xl[(pq * 4 + 3) * 64 + cps] = pack_bf2(a.w, c.w);
    }
    __syncthreads();

    uint4 breg[4][4];
#pragma unroll
    for (int kt = 0; kt < 4; ++kt)
#pragma unroll
        for (int i = 0; i < 4; ++i) {
            const int px = arow * 4 + i;
            const int cp = (kt * 16 + agrp * 4) ^ ((arow & 7) << 2);
            breg[kt][i] = *(const uint4*)&xl[px * 64 + cp];
        }

    for (int gi = 0; gi < 4; ++gi) {
        const int grp = wid + gi * 4;
        const bool isgq = grp >= 12;
        const int och = (isgq ? grp - 12 : grp) * 16;
        const unsigned* wseg = pw + (isgq ? PW_GQ : PW_QKV);
        const float* bsrc = isgq ? gq_b : qkv_b;
        const float bsc = isgq ? 0.25f : 1.0f;

        bf8 afr[4];
#pragma unroll
        for (int kt = 0; kt < 4; ++kt) {
            uint4 t = *(const uint4*)&wseg[(och + arow) * 64 + kt * 16 + agrp * 4];
            afr[kt] = __builtin_bit_cast(bf8, t);
        }

        f4 acc[4];
#pragma unroll
        for (int i = 0; i < 4; ++i) acc[i] = (f4){0.f, 0.f, 0.f, 0.f};
#pragma unroll
        for (int kt = 0; kt < 4; ++kt)
#pragma unroll
            for (int i = 0; i < 4; ++i)
                acc[i] = __builtin_amdgcn_mfma_f32_16x16x32_bf16(
                    afr[kt], __builtin_bit_cast(bf8, breg[kt][i]), acc[i], 0, 0, 0);

        unsigned short* ob = isgq ? gq_out : qkv_out;
        const int ostride = isgq ? 64 : 192;
#pragma unroll
        for (int r = 0; r < 4; ++r) {
            const int o = och + agrp * 4 + r;
            const float bs = bsrc[o] * bsc;
            const float v0 = acc[0][r] + bs, v1 = acc[1][r] + bs;
            const float v2 = acc[2][r] + bs, v3 = acc[3][r] + bs;
            *(uint2*)&ob[((long long)b * ostride + o) * NP + quad * 64 + arow * 4] =
                make_uint2(pack_bf2(v0, v1), pack_bf2(v2, v3));
        }
    }
}

// ---------------------------------------------------------------------------
// MFMA conv1x1 (generic; gkv f32->f32 and proj bf16->f32); weights pre-packed.
// ---------------------------------------------------------------------------
template<int C, int OT, int INBF, int OUTBF>
__global__ __launch_bounds__(256) void k_mfma_conv(
    const void* __restrict__ in0v, const unsigned* __restrict__ pw,
    const float* __restrict__ bias, void* __restrict__ outv,
    int np, long long ibs, int storeO)
{
    constexpr int KT = C / 32;
    const int tid  = threadIdx.x;
    const int lane = tid & 63, wid = tid >> 6;
    const int b    = blockIdx.z;
    const int obq  = blockIdx.y * (OT * 16);
    const int arow = lane & 15, agrp = lane >> 4;
    const int nquad = np >> 6;

    bf8 afr[OT][KT];
#pragma unroll
    for (int ot = 0; ot < OT; ++ot)
#pragma unroll
        for (int kt = 0; kt < KT; ++kt) {
            uint4 t = *(const uint4*)&pw[(obq + ot * 16 + arow) * (C / 2) + kt * 16 + agrp * 4];
            afr[ot][kt] = __builtin_bit_cast(bf8, t);
        }

    const float*          x0f = (const float*)in0v          + (long long)b * (INBF ? 0 : ibs);
    const unsigned short* x0h = (const unsigned short*)in0v + (long long)b * (INBF ? ibs : 0);

    const int quad = blockIdx.x * 4 + wid;
    if (quad >= nquad) return;
    const int p0 = quad * 64 + arow * 4;

    f4 acc[4][OT];
#pragma unroll
    for (int i = 0; i < 4; ++i)
#pragma unroll
        for (int ot = 0; ot < OT; ++ot) acc[i][ot] = (f4){0.f, 0.f, 0.f, 0.f};

#pragma unroll
    for (int kt = 0; kt < KT; ++kt) {
        const long long cbase = kt * 32 + agrp * 8;
        int uu[4][4];
#pragma unroll
        for (int jj = 0; jj < 4; ++jj) {
            if (INBF == 0) {
                float4 a0 = *(const float4*)&x0f[(cbase + 2 * jj) * np + p0];
                float4 a1 = *(const float4*)&x0f[(cbase + 2 * jj + 1) * np + p0];
                uu[0][jj] = (int)pack_bf2(a0.x, a1.x);
                uu[1][jj] = (int)pack_bf2(a0.y, a1.y);
                uu[2][jj] = (int)pack_bf2(a0.z, a1.z);
                uu[3][jj] = (int)pack_bf2(a0.w, a1.w);
            } else {
                ushort4 a0 = *(const ushort4*)&x0h[(cbase + 2 * jj) * np + p0];
                ushort4 a1 = *(const ushort4*)&x0h[(cbase + 2 * jj + 1) * np + p0];
                uu[0][jj] = (int)((unsigned)a0.x | ((unsigned)a1.x << 16));
                uu[1][jj] = (int)((unsigned)a0.y | ((unsigned)a1.y << 16));
                uu[2][jj] = (int)((unsigned)a0.z | ((unsigned)a1.z << 16));
                uu[3][jj] = (int)((unsigned)a0.w | ((unsigned)a1.w << 16));
            }
        }
#pragma unroll
        for (int i = 0; i < 4; ++i) {
            int4 ti = {uu[i][0], uu[i][1], uu[i][2], uu[i][3]};
            bf8 bfr = __builtin_bit_cast(bf8, ti);
#pragma unroll
            for (int ot = 0; ot < OT; ++ot)
                acc[i][ot] = __builtin_amdgcn_mfma_f32_16x16x32_bf16(afr[ot][kt], bfr, acc[i][ot], 0, 0, 0);
        }
    }

#pragma unroll
    for (int ot = 0; ot < OT; ++ot) {
#pragma unroll
        for (int r = 0; r < 4; ++r) {
            const int o = obq + ot * 16 + agrp * 4 + r;
            const float bs = bias[o];
            float4 v;
            v.x = acc[0][ot][r] + bs;
            v.y = acc[1][ot][r] + bs;
            v.z = acc[2][ot][r] + bs;
            v.w = acc[3][ot][r] + bs;
            const long long idx = ((long long)b * storeO + o) * np + p0;
            if (OUTBF == 0) {
                *(float4*)&((float*)outv)[idx] = v;
            } else {
                *(uint2*)&((unsigned short*)outv)[idx] =
                    make_uint2(pack_bf2(v.x, v.y), pack_bf2(v.z, v.w));
            }
        }
    }
}

// ---------------------------------------------------------------------------
// Fused am1+am2 (bf16 I/O); weights pre-packed.
// ---------------------------------------------------------------------------
__global__ __launch_bounds__(256) void k_am_fused(
    const unsigned short* __restrict__ dw,   // bf16: q +0, k +64NP, v +128NP
    const unsigned* __restrict__ pw,
    const float* __restrict__ b1v, const float* __restrict__ b2v,
    unsigned short* __restrict__ hi)         // bf16 hilo ch 0..63
{
    __shared__ __align__(16) uint2 abuf[4][1024];

    const int tid  = threadIdx.x;
    const int lane = tid & 63, wid = tid >> 6;
    const int b    = blockIdx.z;
    const int arow = lane & 15, agrp = lane >> 4;

    bf8 afr1[4][2], afr2[4][2];
#pragma unroll
    for (int ot = 0; ot < 4; ++ot)
#pragma unroll
        for (int kt = 0; kt < 2; ++kt) {
            uint4 t1 = *(const uint4*)&pw[PW_AM1 + (ot * 16 + arow) * 32 + kt * 16 + agrp * 4];
            uint4 t2 = *(const uint4*)&pw[PW_AM2 + (ot * 16 + arow) * 32 + kt * 16 + agrp * 4];
            afr1[ot][kt] = __builtin_bit_cast(bf8, t1);
            afr2[ot][kt] = __builtin_bit_cast(bf8, t2);
        }

    const unsigned short* xq = dw + (long long)b * (192ll * NP);
    const unsigned short* xk = xq + 64ll * NP;
    const unsigned short* xv = xq + 128ll * NP;

    const int quad = blockIdx.x * 4 + wid;
    const int p0 = quad * 64 + arow * 4;

    f4 acc1[4][4];
#pragma unroll
    for (int i = 0; i < 4; ++i)
#pragma unroll
        for (int ot = 0; ot < 4; ++ot) acc1[i][ot] = (f4){0.f, 0.f, 0.f, 0.f};

#pragma unroll
    for (int kt = 0; kt < 2; ++kt) {
        const long long cbase = kt * 32 + agrp * 8;
        int uu[4][4];
#pragma unroll
        for (int jj = 0; jj < 4; ++jj) {
            ushort4 a0 = *(const ushort4*)&xq[(cbase + 2 * jj) * NP + p0];
            ushort4 a1 = *(const ushort4*)&xq[(cbase + 2 * jj + 1) * NP + p0];
            ushort4 y0 = *(const ushort4*)&xk[(cbase + 2 * jj) * NP + p0];
            ushort4 y1 = *(const ushort4*)&xk[(cbase + 2 * jj + 1) * NP + p0];
            uu[0][jj] = (int)pack_bf2(bf2f(a0.x) * bf2f(y0.x), bf2f(a1.x) * bf2f(y1.x));
            uu[1][jj] = (int)pack_bf2(bf2f(a0.y) * bf2f(y0.y), bf2f(a1.y) * bf2f(y1.y));
            uu[2][jj] = (int)pack_bf2(bf2f(a0.z) * bf2f(y0.z), bf2f(a1.z) * bf2f(y1.z));
            uu[3][jj] = (int)pack_bf2(bf2f(a0.w) * bf2f(y0.w), bf2f(a1.w) * bf2f(y1.w));
        }
#pragma unroll
        for (int i = 0; i < 4; ++i) {
            int4 ti = {uu[i][0], uu[i][1], uu[i][2], uu[i][3]};
            bf8 bfr = __builtin_bit_cast(bf8, ti);
#pragma unroll
            for (int ot = 0; ot < 4; ++ot)
                acc1[i][ot] = __builtin_amdgcn_mfma_f32_16x16x32_bf16(afr1[ot][kt], bfr, acc1[i][ot], 0, 0, 0);
        }
    }

#pragma unroll
    for (int i = 0; i < 4; ++i)
#pragma unroll
        for (int ot = 0; ot < 4; ++ot) {
            const int ch0 = ot * 16 + agrp * 4;
            float v0 = acc1[i][ot][0] + b1v[ch0 + 0];
            float v1 = acc1[i][ot][1] + b1v[ch0 + 1];
            float v2 = acc1[i][ot][2] + b1v[ch0 + 2];
            float v3 = acc1[i][ot][3] + b1v[ch0 + 3];
            v0 = v0 / (1.f + __expf(-v0));
            v1 = v1 / (1.f + __expf(-v1));
            v2 = v2 / (1.f + __expf(-v2));
            v3 = v3 / (1.f + __expf(-v3));
            const int c2 = ot * 4 + agrp;
            abuf[wid][(arow * 4 + i) * 16 + (c2 ^ arow)] =
                make_uint2(pack_bf2(v0, v1), pack_bf2(v2, v3));
        }

    f4 acc2[4][4];
#pragma unroll
    for (int i = 0; i < 4; ++i)
#pragma unroll
        for (int ot = 0; ot < 4; ++ot) acc2[i][ot] = (f4){0.f, 0.f, 0.f, 0.f};

#pragma unroll
    for (int kt = 0; kt < 2; ++kt) {
        const int bc2 = kt * 8 + agrp * 2;
#pragma unroll
        for (int i = 0; i < 4; ++i) {
            const uint2 rA = abuf[wid][(arow * 4 + i) * 16 + (bc2 ^ arow)];
            const uint2 rB = abuf[wid][(arow * 4 + i) * 16 + ((bc2 + 1) ^ arow)];
            int4 ti = make_int4((int)rA.x, (int)rA.y, (int)rB.x, (int)rB.y);
            bf8 bfr = __builtin_bit_cast(bf8, ti);
#pragma unroll
            for (int ot = 0; ot < 4; ++ot)
                acc2[i][ot] = __builtin_amdgcn_mfma_f32_16x16x32_bf16(afr2[ot][kt], bfr, acc2[i][ot], 0, 0, 0);
        }
    }

#pragma unroll
    for (int ot = 0; ot < 4; ++ot) {
#pragma unroll
        for (int r = 0; r < 4; ++r) {
            const int o = ot * 16 + agrp * 4 + r;
            const float bs = b2v[o];
            ushort4 vv4 = *(const ushort4*)&xv[(long long)o * NP + p0];
            float h0 = tanhf((acc2[0][ot][r] + bs) * 0.25f) * bf2f(vv4.x);
            float h1 = tanhf((acc2[1][ot][r] + bs) * 0.25f) * bf2f(vv4.y);
            float h2 = tanhf((acc2[2][ot][r] + bs) * 0.25f) * bf2f(vv4.z);
            float h3 = tanhf((acc2[3][ot][r] + bs) * 0.25f) * bf2f(vv4.w);
            *(uint2*)&hi[((long long)b * 128 + o) * NP + p0] =
                make_uint2(pack_bf2(h0, h1), pack_bf2(h2, h3));
        }
    }
}

// ---------------------------------------------------------------------------
// depthwise 5x5, pad 2 — LDS-staged; bf16 in/out.  (unchanged)
// ---------------------------------------------------------------------------
__global__ __launch_bounds__(256) void k_dwconv5_lds(
    const unsigned short* __restrict__ in, const float* __restrict__ w,
    const float* __restrict__ bias, unsigned short* __restrict__ out, int ch_total)
{
    __shared__ __align__(16) float img[NP];
    const int tid = threadIdx.x;
    const int ch  = blockIdx.x;
    const int b   = blockIdx.y;
    const unsigned short* ip = in + ((long long)b * ch_total + ch) * NP;

#pragma unroll
    for (int j = 0; j < 9; ++j) {
        const uint2 rr = ((const uint2*)ip)[tid + 256 * j];
        float4 f;
        f.x = bflo(rr.x); f.y = bfhi(rr.x);
        f.z = bflo(rr.y); f.w = bfhi(rr.y);
        ((float4*)img)[tid + 256 * j] = f;
    }
    __syncthreads();

    const float* wp = w + ch * 25;
    float wr[25];
#pragma unroll
    for (int i = 0; i < 25; ++i) wr[i] = wp[i];
    const float bs = bias[ch];

    unsigned short* op = out + ((long long)b * ch_total + ch) * NP;

#pragma unroll
    for (int j = 0; j < 9; ++j) {
        const int q  = tid + 256 * j;
        const int y  = q / 24;
        const int x4 = (q - y * 24) * 4;
        float o0 = bs, o1 = bs, o2 = bs, o3 = bs;
#pragma unroll
        for (int ky = 0; ky < 5; ++ky) {
            const int yy = y + ky - 2;
            if (yy < 0 || yy >= HH) continue;
            const float* row = &img[yy * WW + x4];
            float4 mid = *(const float4*)row;
            float4 lf  = (x4 >= 4)      ? *(const float4*)(row - 4)
                                        : make_float4(0.f, 0.f, 0.f, 0.f);
            float4 rt  = (x4 + 4 < WW)  ? *(const float4*)(row + 4)
                                        : make_float4(0.f, 0.f, 0.f, 0.f);
            const float f0 = lf.z,  f1 = lf.w;
            const float f2 = mid.x, f3 = mid.y, f4v = mid.z, f5 = mid.w;
            const float f6 = rt.x,  f7 = rt.y;
            const float w0 = wr[ky * 5 + 0], w1 = wr[ky * 5 + 1],
                        w2 = wr[ky * 5 + 2], w3 = wr[ky * 5 + 3],
                        w4 = wr[ky * 5 + 4];
            o0 = fmaf(w0, f0, o0); o0 = fmaf(w1, f1, o0); o0 = fmaf(w2, f2, o0);
            o0 = fmaf(w3, f3, o0); o0 = fmaf(w4, f4v, o0);
            o1 = fmaf(w0, f1, o1); o1 = fmaf(w1, f2, o1); o1 = fmaf(w2, f3, o1);
            o1 = fmaf(w3, f4v, o1); o1 = fmaf(w4, f5, o1);
            o2 = fmaf(w0, f2, o2); o2 = fmaf(w1, f3, o2); o2 = fmaf(w2, f4v, o2);
            o2 = fmaf(w3, f5, o2); o2 = fmaf(w4, f6, o2);
            o3 = fmaf(w0, f3, o3); o3 = fmaf(w1, f4v, o3); o3 = fmaf(w2, f5, o3);
            o3 = fmaf(w3, f6, o3); o3 = fmaf(w4, f7, o3);
        }
        *(uint2*)&op[y * WW + x4] = make_uint2(pack_bf2(o0, o1), pack_bf2(o2, o3));
    }
}

// ---------------------------------------------------------------------------
// 4x4 average pool — float4 loads.
// ---------------------------------------------------------------------------
__global__ __launch_bounds__(256) void k_avgpool4(
    const float* __restrict__ in, float* __restrict__ out)
{
    int idx = blockIdx.x * 256 + threadIdx.x;
    int total = NB * 128 * NPK;
    if (idx >= total) return;
    int pw = idx % 24;
    int t  = idx / 24;
    int ph = t % 24;  t /= 24;
    int c  = t % 128;
    int b  = t / 128;
    const float* ip = in + ((long long)b * 128 + c) * NP + (ph * 4) * WW + pw * 4;
    float4 r0 = *(const float4*)(ip);
    float4 r1 = *(const float4*)(ip + WW);
    float4 r2 = *(const float4*)(ip + 2 * WW);
    float4 r3 = *(const float4*)(ip + 3 * WW);
    float s = ((r0.x + r0.y) + (r0.z + r0.w)) + ((r1.x + r1.y) + (r1.z + r1.w))
            + ((r2.x + r2.y) + (r2.z + r2.w)) + ((r3.x + r3.y) + (r3.z + r3.w));
    out[idx] = s * (1.0f / 16.0f);
}

// ---------------------------------------------------------------------------
// MFMA flash-attention — byte-exact r12 kernel (verified 59.5-60.2 µs).
// ---------------------------------------------------------------------------
__global__ __launch_bounds__(256) void k_attn_mfma(
    const unsigned short* __restrict__ q,  // bf16 (B,64,NP), pre-scaled by 0.25
    const float* __restrict__ kv,          // f32 (B,128,NPK)
    unsigned short* __restrict__ hilo)     // bf16 (B,128,NP), lo at ch 64..127
{
    __shared__ __align__(16) int4  klds4[36 * 32];
    __shared__ __align__(16) int4  zlds4[32];
    __shared__ __align__(16) int4  vlds4[18 * 64];
    __shared__ __align__(16) uint2 elds2[2][4 * 256];

    const int tid  = threadIdx.x;
    const int lane = tid & 63, wid = tid >> 6;
    const int g    = lane >> 4, qi = lane & 15;
    const int bh   = blockIdx.y, b = bh >> 2, h = bh & 3;

    const float* kbase = kv + ((long long)b * 128 + h * 16) * NPK;
    const float* vbase = kv + ((long long)b * 128 + 64 + h * 16) * NPK;

    for (int i = tid; i < 1152; i += 256) {
        const int key = i >> 1, dg = i & 1;
        const float* kp = kbase + (long long)(dg * 8) * NPK + key;
        int4 t;
        t.x = (int)pack_bf2(kp[0],       kp[NPK]);
        t.y = (int)pack_bf2(kp[2 * NPK], kp[3 * NPK]);
        t.z = (int)pack_bf2(kp[4 * NPK], kp[5 * NPK]);
        t.w = (int)pack_bf2(kp[6 * NPK], kp[7 * NPK]);
        klds4[(key >> 4) * 32 + dg * 16 + (key & 15)] = t;
    }
    for (int i = tid; i < 1152; i += 256) {
        const int t = i >> 6, l = i & 63;
        const float* vp = vbase + (long long)(l & 15) * NPK + t * 32 + (l >> 4) * 8;
        float4 a = *(const float4*)vp;
        float4 c = *(const float4*)(vp + 4);
        int4 tt;
        tt.x = (int)pack_bf2(a.x, a.y);
        tt.y = (int)pack_bf2(a.z, a.w);
        tt.z = (int)pack_bf2(c.x, c.y);
        tt.w = (int)pack_bf2(c.z, c.w);
        vlds4[i] = tt;
    }
    if (tid < 32) zlds4[tid] = make_int4(0, 0, 0, 0);
    __syncthreads();

    const int q0 = (blockIdx.x * 4 + wid) * 32;
    const unsigned short* qcol = q + ((long long)b * 64 + h * 16) * NP + q0 + qi;
    int4 qv[2] = { make_int4(0, 0, 0, 0), make_int4(0, 0, 0, 0) };
    if (g < 2) {
#pragma unroll
        for (int s = 0; s < 2; ++s) {
            const unsigned short* qp = qcol + s * 16 + (long long)(g * 8) * NP;
            qv[s].x = (int)((unsigned)qp[0]          | ((unsigned)qp[(long long)NP]     << 16));
            qv[s].y = (int)((unsigned)qp[2ll * NP]   | ((unsigned)qp[3ll * NP]          << 16));
            qv[s].z = (int)((unsigned)qp[4ll * NP]   | ((unsigned)qp[5ll * NP]          << 16));
            qv[s].w = (int)((unsigned)qp[6ll * NP]   | ((unsigned)qp[7ll * NP]          << 16));
        }
    }

    f4 accp[2] = { (f4){0.f, 0.f, 0.f, 0.f}, (f4){0.f, 0.f, 0.f, 0.f} };
    float den[2] = { 0.f, 0.f };

    auto QKEXP = [&](int k2, int buf) {
#pragma unroll
        for (int tp = 0; tp < 2; ++tp) {
            const int4 kf = (lane < 32) ? klds4[(k2 * 2 + tp) * 32 + lane]
                                        : zlds4[lane & 31];
            const bf8 ka = __builtin_bit_cast(bf8, kf);
#pragma unroll
            for (int s = 0; s < 2; ++s) {
                f4 sa = __builtin_amdgcn_mfma_f32_16x16x32_bf16(
                    ka, __builtin_bit_cast(bf8, qv[s]), (f4){0.f, 0.f, 0.f, 0.f}, 0, 0, 0);
                const float e0 = __expf(sa[0]), e1 = __expf(sa[1]);
                const float e2 = __expf(sa[2]), e3 = __expf(sa[3]);
                den[s] += (e0 + e1) + (e2 + e3);
                elds2[buf][wid * 256 + s * 128 + tp * 64 + g * 16 + qi] =
                    make_uint2(pack_bf2(e0, e1), pack_bf2(e2, e3));
            }
        }
    };
    auto PV = [&](int k2, int buf) {
        const bf8 va = __builtin_bit_cast(bf8, vlds4[k2 * 64 + lane]);
#pragma unroll
        for (int s = 0; s < 2; ++s) {
            const int base = wid * 256 + s * 128 + (g >> 1) * 64 + (g & 1) * 32 + qi;
            const uint2 r0 = elds2[buf][base];
            const uint2 r1 = elds2[buf][base + 16];
            int4 ti = make_int4((int)r0.x, (int)r0.y, (int)r1.x, (int)r1.y);
            accp[s] = __builtin_amdgcn_mfma_f32_16x16x32_bf16(
                va, __builtin_bit_cast(bf8, ti), accp[s], 0, 0, 0);
        }
    };

    QKEXP(0, 0);
    for (int k2 = 0; k2 < 17; ++k2) {
        QKEXP(k2 + 1, (k2 + 1) & 1);
        PV(k2, k2 & 1);
    }
    PV(17, 1);

#pragma unroll
    for (int s = 0; s < 2; ++s) {
        float d0 = den[s];
        d0 += __shfl_xor(d0, 16, 64);
        d0 += __shfl_xor(d0, 32, 64);
        const float inv = 1.0f / d0;
        unsigned short* op = hilo + ((long long)b * 128 + 64 + h * 16 + g * 4) * NP + q0 + s * 16 + qi;
#pragma unroll
        for (int r = 0; r < 4; ++r)
            op[(long long)r * NP] = f2bfu(accp[s][r] * inv);
    }
}

// ---------------------------------------------------------------------------
extern "C" void kernel_launch(void* const* d_in, const int* in_sizes, int n_in,
                              void* d_out, int out_size, void* d_ws, size_t ws_size,
                              hipStream_t stream)
{
    const float* x      = (const float*)d_in[0];
    const float* qkv_w  = (const float*)d_in[1];
    const float* qkv_b  = (const float*)d_in[2];
    const float* dw_w   = (const float*)d_in[3];
    const float* dw_b   = (const float*)d_in[4];
    const float* am_w1  = (const float*)d_in[5];
    const float* am_b1  = (const float*)d_in[6];
    const float* am_w2  = (const float*)d_in[7];
    const float* am_b2  = (const float*)d_in[8];
    const float* gq_w   = (const float*)d_in[9];
    const float* gq_b   = (const float*)d_in[10];
    const float* gkv_w  = (const float*)d_in[11];
    const float* gkv_b  = (const float*)d_in[12];
    const float* proj_w = (const float*)d_in[13];
    const float* proj_b = (const float*)d_in[14];
    float* out = (float*)d_out;
    char* wsb = (char*)d_ws;

    // byte layout (no overlaps):
    //   [0, 28311552)          t_qkv bf16 (8,192,9216); t_hilo reuses after dwconv
    //   [28311552, 56623104)   t_dw  bf16 (8,192,9216)
    //   [56623104, 66060288)   t_gq  bf16 (8,64,9216)
    //   [66060288, 68419584)   t_pool f32 (8,128,576)
    //   [68419584, 70778880)   t_gkv  f32 (8,128,576)
    //   [70778880, 70926336)   t_pw   packed weights (147KB)
    unsigned short* t_qkv  = (unsigned short*)wsb;
    unsigned short* t_hilo = (unsigned short*)wsb;
    unsigned short* t_dw   = (unsigned short*)(wsb + 28311552);
    unsigned short* t_gq   = (unsigned short*)(wsb + 56623104);
    float*          t_pool = (float*)(wsb + 66060288);
    float*          t_gkv  = (float*)(wsb + 68419584);
    unsigned*       t_pw   = (unsigned*)(wsb + 70778880);

    // 0. pre-pack all conv weights (gq scaled 0.25)
    k_packw<<<dim3((PW_TOTAL + 255) / 256), 256, 0, stream>>>(
        qkv_w, gq_w, gkv_w, am_w1, am_w2, proj_w, t_pw);
    // 1. qkv (bf16) + gq (bf16, *0.25) from one LDS-staged read of x
    k_qkvgq<<<dim3(144, 1, NB), 256, 0, stream>>>(
        x, t_pw, qkv_b, gq_b, t_qkv, t_gq);
    // 2. depthwise 5x5 (bf16 in -> bf16 out)
    k_dwconv5_lds<<<dim3(192, NB), 256, 0, stream>>>(t_qkv, dw_w, dw_b, t_dw, 192);
    // 3. pooled = avgpool4(x)
    k_avgpool4<<<dim3((NB*128*NPK + 255)/256), 256, 0, stream>>>(x, t_pool);
    // 4. gkv = conv1x1(pooled)  f32 out
    k_mfma_conv<128,4,0,0><<<dim3(3,2,NB), 256, 0, stream>>>(
        t_pool, t_pw + PW_GKV, gkv_b, t_gkv, NPK, (long long)128 * NPK, 128);
    // 5. fused am -> hilo ch 0..63 (bf16)
    k_am_fused<<<dim3(36,1,NB), 256, 0, stream>>>(
        t_dw, t_pw, am_b1, am_b2, t_hilo);
    // 6. attention (r12-exact) -> hilo ch 64..127 (bf16)
    k_attn_mfma<<<dim3(72, 32), 256, 0, stream>>>(t_gq, t_gkv, t_hilo);
    // 7. out = conv1x1(hilo bf16, proj_w)  f32 out
    k_mfma_conv<128,4,1,0><<<dim3(36,2,NB), 256, 0, stream>>>(
        t_hilo, t_pw + PW_PROJ, proj_b, out, NP, (long long)128 * NP, 128);
}

// Round 18
// 154.032 us; speedup vs baseline: 1.2195x; 1.0087x over previous
//
#include <hip/hip_runtime.h>
#include <hip/hip_bf16.h>
#include <hip/hip_fp16.h>
#include <cstdint>

static constexpr int NB  = 8;
static constexpr int HH  = 96;
static constexpr int WW  = 96;
static constexpr int NP  = 9216;   // 96*96
static constexpr int NPK = 576;    // 24*24

using bf8 = __attribute__((ext_vector_type(8))) short;
using f4  = __attribute__((ext_vector_type(4))) float;

__device__ __forceinline__ unsigned pack_bf2(float a, float b) {
    __hip_bfloat162 h = __float22bfloat162_rn(make_float2(a, b));
    unsigned u; __builtin_memcpy(&u, &h, 4);
    return u;
}
__device__ __forceinline__ unsigned short f2bfu(float f) {
    __hip_bfloat16 h = __float2bfloat16(f);
    unsigned short u; __builtin_memcpy(&u, &h, 2);
    return u;
}
__device__ __forceinline__ float bf2f(unsigned short u) {
    unsigned v = (unsigned)u << 16;
    float f; __builtin_memcpy(&f, &v, 4);
    return f;
}
__device__ __forceinline__ float bflo(unsigned p) {
    unsigned v = p << 16; float f; __builtin_memcpy(&f, &v, 4); return f;
}
__device__ __forceinline__ float bfhi(unsigned p) {
    unsigned v = p & 0xffff0000u; float f; __builtin_memcpy(&f, &v, 4); return f;
}

// packed-weight segment offsets (uints)
static constexpr int PW_QKV  = 0;       // 192*64
static constexpr int PW_GQ   = 12288;   // 64*64  (scaled 0.25)
static constexpr int PW_GKV  = 16384;   // 128*64
static constexpr int PW_AM1  = 24576;   // 64*32
static constexpr int PW_AM2  = 26624;   // 64*32
static constexpr int PW_PROJ = 28672;   // 128*64
static constexpr int PW_TOTAL= 36864;

// ---------------------------------------------------------------------------
// One-time weight pre-pack (gq segment scaled 0.25).
// ---------------------------------------------------------------------------
__global__ __launch_bounds__(256) void k_packw(
    const float* __restrict__ qkv_w, const float* __restrict__ gq_w,
    const float* __restrict__ gkv_w, const float* __restrict__ am_w1,
    const float* __restrict__ am_w2, const float* __restrict__ proj_w,
    unsigned* __restrict__ pw)
{
    const int idx = blockIdx.x * 256 + threadIdx.x;
    if (idx >= PW_TOTAL) return;
    const float* src; int j2; float sc = 1.0f;
    if (idx < PW_GQ)          { src = qkv_w;  j2 = (idx - PW_QKV) * 2; }
    else if (idx < PW_GKV)    { src = gq_w;   j2 = (idx - PW_GQ) * 2;  sc = 0.25f; }
    else if (idx < PW_AM1)    { src = gkv_w;  j2 = (idx - PW_GKV) * 2; }
    else if (idx < PW_AM2)    { src = am_w1;  j2 = (idx - PW_AM1) * 2; }
    else if (idx < PW_PROJ)   { src = am_w2;  j2 = (idx - PW_AM2) * 2; }
    else                      { src = proj_w; j2 = (idx - PW_PROJ) * 2; }
    pw[idx] = pack_bf2(src[j2] * sc, src[j2 + 1] * sc);
}

// ---------------------------------------------------------------------------
// Fused qkv+gq conv1x1 with LDS-staged x; weights pre-packed. (r17, unchanged)
// ---------------------------------------------------------------------------
__global__ __launch_bounds__(256) void k_qkvgq(
    const float* __restrict__ x, const unsigned* __restrict__ pw,
    const float* __restrict__ qkv_b, const float* __restrict__ gq_b,
    unsigned short* __restrict__ qkv_out,   // bf16 (B,192,NP)
    unsigned short* __restrict__ gq_out)    // bf16 (B,64,NP), pre-scaled 0.25
{
    __shared__ __align__(16) unsigned xl[64 * 64];   // 16KB
    const int tid  = threadIdx.x;
    const int lane = tid & 63, wid = tid >> 6;
    const int quad = blockIdx.x, b = blockIdx.z;
    const int arow = lane & 15, agrp = lane >> 4;

    const float* xb = x + (long long)b * 128 * NP + quad * 64;

#pragma unroll
    for (int it = 0; it < 4; ++it) {
        const int task = tid + 256 * it;
        const int cp = task >> 4, pq = task & 15;
        float4 a = *(const float4*)&xb[(long long)(2 * cp) * NP + pq * 4];
        float4 c = *(const float4*)&xb[(long long)(2 * cp + 1) * NP + pq * 4];
        const int cps = cp ^ ((pq & 7) << 2);
        xl[(pq * 4 + 0) * 64 + cps] = pack_bf2(a.x, c.x);
        xl[(pq * 4 + 1) * 64 + cps] = pack_bf2(a.y, c.y);
        xl[(pq * 4 + 2) * 64 + cps] = pack_bf2(a.z, c.z);
        xl[(pq * 4 + 3) * 64 + cps] = pack_bf2(a.w, c.w);
    }
    __syncthreads();

    uint4 breg[4][4];
#pragma unroll
    for (int kt = 0; kt < 4; ++kt)
#pragma unroll
        for (int i = 0; i < 4; ++i) {
            const int px = arow * 4 + i;
            const int cp = (kt * 16 + agrp * 4) ^ ((arow & 7) << 2);
            breg[kt][i] = *(const uint4*)&xl[px * 64 + cp];
        }

    for (int gi = 0; gi < 4; ++gi) {
        const int grp = wid + gi * 4;
        const bool isgq = grp >= 12;
        const int och = (isgq ? grp - 12 : grp) * 16;
        const unsigned* wseg = pw + (isgq ? PW_GQ : PW_QKV);
        const float* bsrc = isgq ? gq_b : qkv_b;
        const float bsc = isgq ? 0.25f : 1.0f;

        bf8 afr[4];
#pragma unroll
        for (int kt = 0; kt < 4; ++kt) {
            uint4 t = *(const uint4*)&wseg[(och + arow) * 64 + kt * 16 + agrp * 4];
            afr[kt] = __builtin_bit_cast(bf8, t);
        }

        f4 acc[4];
#pragma unroll
        for (int i = 0; i < 4; ++i) acc[i] = (f4){0.f, 0.f, 0.f, 0.f};
#pragma unroll
        for (int kt = 0; kt < 4; ++kt)
#pragma unroll
            for (int i = 0; i < 4; ++i)
                acc[i] = __builtin_amdgcn_mfma_f32_16x16x32_bf16(
                    afr[kt], __builtin_bit_cast(bf8, breg[kt][i]), acc[i], 0, 0, 0);

        unsigned short* ob = isgq ? gq_out : qkv_out;
        const int ostride = isgq ? 64 : 192;
#pragma unroll
        for (int r = 0; r < 4; ++r) {
            const int o = och + agrp * 4 + r;
            const float bs = bsrc[o] * bsc;
            const float v0 = acc[0][r] + bs, v1 = acc[1][r] + bs;
            const float v2 = acc[2][r] + bs, v3 = acc[3][r] + bs;
            *(uint2*)&ob[((long long)b * ostride + o) * NP + quad * 64 + arow * 4] =
                make_uint2(pack_bf2(v0, v1), pack_bf2(v2, v3));
        }
    }
}

// ---------------------------------------------------------------------------
// MFMA conv1x1 (generic; gkv f32->f32 and proj bf16->f32); weights pre-packed.
// ---------------------------------------------------------------------------
template<int C, int OT, int INBF, int OUTBF>
__global__ __launch_bounds__(256) void k_mfma_conv(
    const void* __restrict__ in0v, const unsigned* __restrict__ pw,
    const float* __restrict__ bias, void* __restrict__ outv,
    int np, long long ibs, int storeO)
{
    constexpr int KT = C / 32;
    const int tid  = threadIdx.x;
    const int lane = tid & 63, wid = tid >> 6;
    const int b    = blockIdx.z;
    const int obq  = blockIdx.y * (OT * 16);
    const int arow = lane & 15, agrp = lane >> 4;
    const int nquad = np >> 6;

    bf8 afr[OT][KT];
#pragma unroll
    for (int ot = 0; ot < OT; ++ot)
#pragma unroll
        for (int kt = 0; kt < KT; ++kt) {
            uint4 t = *(const uint4*)&pw[(obq + ot * 16 + arow) * (C / 2) + kt * 16 + agrp * 4];
            afr[ot][kt] = __builtin_bit_cast(bf8, t);
        }

    const float*          x0f = (const float*)in0v          + (long long)b * (INBF ? 0 : ibs);
    const unsigned short* x0h = (const unsigned short*)in0v + (long long)b * (INBF ? ibs : 0);

    const int quad = blockIdx.x * 4 + wid;
    if (quad >= nquad) return;
    const int p0 = quad * 64 + arow * 4;

    f4 acc[4][OT];
#pragma unroll
    for (int i = 0; i < 4; ++i)
#pragma unroll
        for (int ot = 0; ot < OT; ++ot) acc[i][ot] = (f4){0.f, 0.f, 0.f, 0.f};

#pragma unroll
    for (int kt = 0; kt < KT; ++kt) {
        const long long cbase = kt * 32 + agrp * 8;
        int uu[4][4];
#pragma unroll
        for (int jj = 0; jj < 4; ++jj) {
            if (INBF == 0) {
                float4 a0 = *(const float4*)&x0f[(cbase + 2 * jj) * np + p0];
                float4 a1 = *(const float4*)&x0f[(cbase + 2 * jj + 1) * np + p0];
                uu[0][jj] = (int)pack_bf2(a0.x, a1.x);
                uu[1][jj] = (int)pack_bf2(a0.y, a1.y);
                uu[2][jj] = (int)pack_bf2(a0.z, a1.z);
                uu[3][jj] = (int)pack_bf2(a0.w, a1.w);
            } else {
                ushort4 a0 = *(const ushort4*)&x0h[(cbase + 2 * jj) * np + p0];
                ushort4 a1 = *(const ushort4*)&x0h[(cbase + 2 * jj + 1) * np + p0];
                uu[0][jj] = (int)((unsigned)a0.x | ((unsigned)a1.x << 16));
                uu[1][jj] = (int)((unsigned)a0.y | ((unsigned)a1.y << 16));
                uu[2][jj] = (int)((unsigned)a0.z | ((unsigned)a1.z << 16));
                uu[3][jj] = (int)((unsigned)a0.w | ((unsigned)a1.w << 16));
            }
        }
#pragma unroll
        for (int i = 0; i < 4; ++i) {
            int4 ti = {uu[i][0], uu[i][1], uu[i][2], uu[i][3]};
            bf8 bfr = __builtin_bit_cast(bf8, ti);
#pragma unroll
            for (int ot = 0; ot < OT; ++ot)
                acc[i][ot] = __builtin_amdgcn_mfma_f32_16x16x32_bf16(afr[ot][kt], bfr, acc[i][ot], 0, 0, 0);
        }
    }

#pragma unroll
    for (int ot = 0; ot < OT; ++ot) {
#pragma unroll
        for (int r = 0; r < 4; ++r) {
            const int o = obq + ot * 16 + agrp * 4 + r;
            const float bs = bias[o];
            float4 v;
            v.x = acc[0][ot][r] + bs;
            v.y = acc[1][ot][r] + bs;
            v.z = acc[2][ot][r] + bs;
            v.w = acc[3][ot][r] + bs;
            const long long idx = ((long long)b * storeO + o) * np + p0;
            if (OUTBF == 0) {
                *(float4*)&((float*)outv)[idx] = v;
            } else {
                *(uint2*)&((unsigned short*)outv)[idx] =
                    make_uint2(pack_bf2(v.x, v.y), pack_bf2(v.z, v.w));
            }
        }
    }
}

// ---------------------------------------------------------------------------
// Merged am + attention kernel.  Blocks 0..287: am (writes hilo ch 0..63);
// blocks 288..2591: attn (writes hilo ch 64..127).  Data-independent; am
// blocks dispatched first and drain inside attn's latency-bound execution.
// LDS: one 53760-byte region; am uses first 32KB, attn carves all of it.
// Both bodies byte-identical in logic to r17's passing kernels.
// ---------------------------------------------------------------------------
__global__ __launch_bounds__(256) void k_am_attn(
    const unsigned short* __restrict__ dw, const unsigned* __restrict__ pw,
    const float* __restrict__ b1v, const float* __restrict__ b2v,
    const unsigned short* __restrict__ q, const float* __restrict__ kv,
    unsigned short* __restrict__ hilo)
{
    __shared__ __align__(16) char smem[53760];
    const int bid = blockIdx.x;
    const int tid = threadIdx.x;
    const int lane = tid & 63, wid = tid >> 6;

    if (bid < 288) {
        // ================= am path =================
        uint2* abuf = (uint2*)smem;            // [4][1024], 32KB
        const int b = bid / 36;
        const int arow = lane & 15, agrp = lane >> 4;

        bf8 afr1[4][2], afr2[4][2];
#pragma unroll
        for (int ot = 0; ot < 4; ++ot)
#pragma unroll
            for (int kt = 0; kt < 2; ++kt) {
                uint4 t1 = *(const uint4*)&pw[PW_AM1 + (ot * 16 + arow) * 32 + kt * 16 + agrp * 4];
                uint4 t2 = *(const uint4*)&pw[PW_AM2 + (ot * 16 + arow) * 32 + kt * 16 + agrp * 4];
                afr1[ot][kt] = __builtin_bit_cast(bf8, t1);
                afr2[ot][kt] = __builtin_bit_cast(bf8, t2);
            }

        const unsigned short* xq = dw + (long long)b * (192ll * NP);
        const unsigned short* xk = xq + 64ll * NP;
        const unsigned short* xv = xq + 128ll * NP;

        const int quad = (bid % 36) * 4 + wid;
        const int p0 = quad * 64 + arow * 4;

        f4 acc1[4][4];
#pragma unroll
        for (int i = 0; i < 4; ++i)
#pragma unroll
            for (int ot = 0; ot < 4; ++ot) acc1[i][ot] = (f4){0.f, 0.f, 0.f, 0.f};

#pragma unroll
        for (int kt = 0; kt < 2; ++kt) {
            const long long cbase = kt * 32 + agrp * 8;
            int uu[4][4];
#pragma unroll
            for (int jj = 0; jj < 4; ++jj) {
                ushort4 a0 = *(const ushort4*)&xq[(cbase + 2 * jj) * NP + p0];
                ushort4 a1 = *(const ushort4*)&xq[(cbase + 2 * jj + 1) * NP + p0];
                ushort4 y0 = *(const ushort4*)&xk[(cbase + 2 * jj) * NP + p0];
                ushort4 y1 = *(const ushort4*)&xk[(cbase + 2 * jj + 1) * NP + p0];
                uu[0][jj] = (int)pack_bf2(bf2f(a0.x) * bf2f(y0.x), bf2f(a1.x) * bf2f(y1.x));
                uu[1][jj] = (int)pack_bf2(bf2f(a0.y) * bf2f(y0.y), bf2f(a1.y) * bf2f(y1.y));
                uu[2][jj] = (int)pack_bf2(bf2f(a0.z) * bf2f(y0.z), bf2f(a1.z) * bf2f(y1.z));
                uu[3][jj] = (int)pack_bf2(bf2f(a0.w) * bf2f(y0.w), bf2f(a1.w) * bf2f(y1.w));
            }
#pragma unroll
            for (int i = 0; i < 4; ++i) {
                int4 ti = {uu[i][0], uu[i][1], uu[i][2], uu[i][3]};
                bf8 bfr = __builtin_bit_cast(bf8, ti);
#pragma unroll
                for (int ot = 0; ot < 4; ++ot)
                    acc1[i][ot] = __builtin_amdgcn_mfma_f32_16x16x32_bf16(afr1[ot][kt], bfr, acc1[i][ot], 0, 0, 0);
            }
        }

#pragma unroll
        for (int i = 0; i < 4; ++i)
#pragma unroll
            for (int ot = 0; ot < 4; ++ot) {
                const int ch0 = ot * 16 + agrp * 4;
                float v0 = acc1[i][ot][0] + b1v[ch0 + 0];
                float v1 = acc1[i][ot][1] + b1v[ch0 + 1];
                float v2 = acc1[i][ot][2] + b1v[ch0 + 2];
                float v3 = acc1[i][ot][3] + b1v[ch0 + 3];
                v0 = v0 / (1.f + __expf(-v0));
                v1 = v1 / (1.f + __expf(-v1));
                v2 = v2 / (1.f + __expf(-v2));
                v3 = v3 / (1.f + __expf(-v3));
                const int c2 = ot * 4 + agrp;
                abuf[wid * 1024 + (arow * 4 + i) * 16 + (c2 ^ arow)] =
                    make_uint2(pack_bf2(v0, v1), pack_bf2(v2, v3));
            }

        f4 acc2[4][4];
#pragma unroll
        for (int i = 0; i < 4; ++i)
#pragma unroll
            for (int ot = 0; ot < 4; ++ot) acc2[i][ot] = (f4){0.f, 0.f, 0.f, 0.f};

#pragma unroll
        for (int kt = 0; kt < 2; ++kt) {
            const int bc2 = kt * 8 + agrp * 2;
#pragma unroll
            for (int i = 0; i < 4; ++i) {
                const uint2 rA = abuf[wid * 1024 + (arow * 4 + i) * 16 + (bc2 ^ arow)];
                const uint2 rB = abuf[wid * 1024 + (arow * 4 + i) * 16 + ((bc2 + 1) ^ arow)];
                int4 ti = make_int4((int)rA.x, (int)rA.y, (int)rB.x, (int)rB.y);
                bf8 bfr = __builtin_bit_cast(bf8, ti);
#pragma unroll
                for (int ot = 0; ot < 4; ++ot)
                    acc2[i][ot] = __builtin_amdgcn_mfma_f32_16x16x32_bf16(afr2[ot][kt], bfr, acc2[i][ot], 0, 0, 0);
            }
        }

#pragma unroll
        for (int ot = 0; ot < 4; ++ot) {
#pragma unroll
            for (int r = 0; r < 4; ++r) {
                const int o = ot * 16 + agrp * 4 + r;
                const float bs = b2v[o];
                ushort4 vv4 = *(const ushort4*)&xv[(long long)o * NP + p0];
                float h0 = tanhf((acc2[0][ot][r] + bs) * 0.25f) * bf2f(vv4.x);
                float h1 = tanhf((acc2[1][ot][r] + bs) * 0.25f) * bf2f(vv4.y);
                float h2 = tanhf((acc2[2][ot][r] + bs) * 0.25f) * bf2f(vv4.z);
                float h3 = tanhf((acc2[3][ot][r] + bs) * 0.25f) * bf2f(vv4.w);
                *(uint2*)&hilo[((long long)b * 128 + o) * NP + p0] =
                    make_uint2(pack_bf2(h0, h1), pack_bf2(h2, h3));
            }
        }
        return;
    }

    // ================= attn path (r12-exact logic) =================
    int4*  klds4 = (int4*)smem;                    // 1152 * 16B = 18432
    int4*  zlds4 = (int4*)(smem + 18432);          // 32 * 16B   = 512
    int4*  vlds4 = (int4*)(smem + 18944);          // 1152 * 16B = 18432
    uint2* elds2 = (uint2*)(smem + 37376);         // 2048 * 8B  = 16384 -> 53760

    const int flat = bid - 288;
    const int bx = flat % 72, bh = flat / 72;
    const int g = lane >> 4, qi = lane & 15;
    const int b = bh >> 2, h = bh & 3;

    const float* kbase = kv + ((long long)b * 128 + h * 16) * NPK;
    const float* vbase = kv + ((long long)b * 128 + 64 + h * 16) * NPK;

    for (int i = tid; i < 1152; i += 256) {
        const int key = i >> 1, dg = i & 1;
        const float* kp = kbase + (long long)(dg * 8) * NPK + key;
        int4 t;
        t.x = (int)pack_bf2(kp[0],       kp[NPK]);
        t.y = (int)pack_bf2(kp[2 * NPK], kp[3 * NPK]);
        t.z = (int)pack_bf2(kp[4 * NPK], kp[5 * NPK]);
        t.w = (int)pack_bf2(kp[6 * NPK], kp[7 * NPK]);
        klds4[(key >> 4) * 32 + dg * 16 + (key & 15)] = t;
    }
    for (int i = tid; i < 1152; i += 256) {
        const int t = i >> 6, l = i & 63;
        const float* vp = vbase + (long long)(l & 15) * NPK + t * 32 + (l >> 4) * 8;
        float4 a = *(const float4*)vp;
        float4 c = *(const float4*)(vp + 4);
        int4 tt;
        tt.x = (int)pack_bf2(a.x, a.y);
        tt.y = (int)pack_bf2(a.z, a.w);
        tt.z = (int)pack_bf2(c.x, c.y);
        tt.w = (int)pack_bf2(c.z, c.w);
        vlds4[i] = tt;
    }
    if (tid < 32) zlds4[tid] = make_int4(0, 0, 0, 0);
    __syncthreads();

    const int q0 = (bx * 4 + wid) * 32;
    const unsigned short* qcol = q + ((long long)b * 64 + h * 16) * NP + q0 + qi;
    int4 qv[2] = { make_int4(0, 0, 0, 0), make_int4(0, 0, 0, 0) };
    if (g < 2) {
#pragma unroll
        for (int s = 0; s < 2; ++s) {
            const unsigned short* qp = qcol + s * 16 + (long long)(g * 8) * NP;
            qv[s].x = (int)((unsigned)qp[0]          | ((unsigned)qp[(long long)NP]     << 16));
            qv[s].y = (int)((unsigned)qp[2ll * NP]   | ((unsigned)qp[3ll * NP]          << 16));
            qv[s].z = (int)((unsigned)qp[4ll * NP]   | ((unsigned)qp[5ll * NP]          << 16));
            qv[s].w = (int)((unsigned)qp[6ll * NP]   | ((unsigned)qp[7ll * NP]          << 16));
        }
    }

    f4 accp[2] = { (f4){0.f, 0.f, 0.f, 0.f}, (f4){0.f, 0.f, 0.f, 0.f} };
    float den[2] = { 0.f, 0.f };

    auto QKEXP = [&](int k2, int buf) {
#pragma unroll
        for (int tp = 0; tp < 2; ++tp) {
            const int4 kf = (lane < 32) ? klds4[(k2 * 2 + tp) * 32 + lane]
                                        : zlds4[lane & 31];
            const bf8 ka = __builtin_bit_cast(bf8, kf);
#pragma unroll
            for (int s = 0; s < 2; ++s) {
                f4 sa = __builtin_amdgcn_mfma_f32_16x16x32_bf16(
                    ka, __builtin_bit_cast(bf8, qv[s]), (f4){0.f, 0.f, 0.f, 0.f}, 0, 0, 0);
                const float e0 = __expf(sa[0]), e1 = __expf(sa[1]);
                const float e2 = __expf(sa[2]), e3 = __expf(sa[3]);
                den[s] += (e0 + e1) + (e2 + e3);
                elds2[buf * 1024 + wid * 256 + s * 128 + tp * 64 + g * 16 + qi] =
                    make_uint2(pack_bf2(e0, e1), pack_bf2(e2, e3));
            }
        }
    };
    auto PV = [&](int k2, int buf) {
        const bf8 va = __builtin_bit_cast(bf8, vlds4[k2 * 64 + lane]);
#pragma unroll
        for (int s = 0; s < 2; ++s) {
            const int base = buf * 1024 + wid * 256 + s * 128 + (g >> 1) * 64 + (g & 1) * 32 + qi;
            const uint2 r0 = elds2[base];
            const uint2 r1 = elds2[base + 16];
            int4 ti = make_int4((int)r0.x, (int)r0.y, (int)r1.x, (int)r1.y);
            accp[s] = __builtin_amdgcn_mfma_f32_16x16x32_bf16(
                va, __builtin_bit_cast(bf8, ti), accp[s], 0, 0, 0);
        }
    };

    QKEXP(0, 0);
    for (int k2 = 0; k2 < 17; ++k2) {
        QKEXP(k2 + 1, (k2 + 1) & 1);
        PV(k2, k2 & 1);
    }
    PV(17, 1);

#pragma unroll
    for (int s = 0; s < 2; ++s) {
        float d0 = den[s];
        d0 += __shfl_xor(d0, 16, 64);
        d0 += __shfl_xor(d0, 32, 64);
        const float inv = 1.0f / d0;
        unsigned short* op = hilo + ((long long)b * 128 + 64 + h * 16 + g * 4) * NP + q0 + s * 16 + qi;
#pragma unroll
        for (int r = 0; r < 4; ++r)
            op[(long long)r * NP] = f2bfu(accp[s][r] * inv);
    }
}

// ---------------------------------------------------------------------------
// depthwise 5x5, pad 2 — LDS-staged; bf16 in/out.  (unchanged)
// ---------------------------------------------------------------------------
__global__ __launch_bounds__(256) void k_dwconv5_lds(
    const unsigned short* __restrict__ in, const float* __restrict__ w,
    const float* __restrict__ bias, unsigned short* __restrict__ out, int ch_total)
{
    __shared__ __align__(16) float img[NP];
    const int tid = threadIdx.x;
    const int ch  = blockIdx.x;
    const int b   = blockIdx.y;
    const unsigned short* ip = in + ((long long)b * ch_total + ch) * NP;

#pragma unroll
    for (int j = 0; j < 9; ++j) {
        const uint2 rr = ((const uint2*)ip)[tid + 256 * j];
        float4 f;
        f.x = bflo(rr.x); f.y = bfhi(rr.x);
        f.z = bflo(rr.y); f.w = bfhi(rr.y);
        ((float4*)img)[tid + 256 * j] = f;
    }
    __syncthreads();

    const float* wp = w + ch * 25;
    float wr[25];
#pragma unroll
    for (int i = 0; i < 25; ++i) wr[i] = wp[i];
    const float bs = bias[ch];

    unsigned short* op = out + ((long long)b * ch_total + ch) * NP;

#pragma unroll
    for (int j = 0; j < 9; ++j) {
        const int q  = tid + 256 * j;
        const int y  = q / 24;
        const int x4 = (q - y * 24) * 4;
        float o0 = bs, o1 = bs, o2 = bs, o3 = bs;
#pragma unroll
        for (int ky = 0; ky < 5; ++ky) {
            const int yy = y + ky - 2;
            if (yy < 0 || yy >= HH) continue;
            const float* row = &img[yy * WW + x4];
            float4 mid = *(const float4*)row;
            float4 lf  = (x4 >= 4)      ? *(const float4*)(row - 4)
                                        : make_float4(0.f, 0.f, 0.f, 0.f);
            float4 rt  = (x4 + 4 < WW)  ? *(const float4*)(row + 4)
                                        : make_float4(0.f, 0.f, 0.f, 0.f);
            const float f0 = lf.z,  f1 = lf.w;
            const float f2 = mid.x, f3 = mid.y, f4v = mid.z, f5 = mid.w;
            const float f6 = rt.x,  f7 = rt.y;
            const float w0 = wr[ky * 5 + 0], w1 = wr[ky * 5 + 1],
                        w2 = wr[ky * 5 + 2], w3 = wr[ky * 5 + 3],
                        w4 = wr[ky * 5 + 4];
            o0 = fmaf(w0, f0, o0); o0 = fmaf(w1, f1, o0); o0 = fmaf(w2, f2, o0);
            o0 = fmaf(w3, f3, o0); o0 = fmaf(w4, f4v, o0);
            o1 = fmaf(w0, f1, o1); o1 = fmaf(w1, f2, o1); o1 = fmaf(w2, f3, o1);
            o1 = fmaf(w3, f4v, o1); o1 = fmaf(w4, f5, o1);
            o2 = fmaf(w0, f2, o2); o2 = fmaf(w1, f3, o2); o2 = fmaf(w2, f4v, o2);
            o2 = fmaf(w3, f5, o2); o2 = fmaf(w4, f6, o2);
            o3 = fmaf(w0, f3, o3); o3 = fmaf(w1, f4v, o3); o3 = fmaf(w2, f5, o3);
            o3 = fmaf(w3, f6, o3); o3 = fmaf(w4, f7, o3);
        }
        *(uint2*)&op[y * WW + x4] = make_uint2(pack_bf2(o0, o1), pack_bf2(o2, o3));
    }
}

// ---------------------------------------------------------------------------
// 4x4 average pool — float4 loads.
// ---------------------------------------------------------------------------
__global__ __launch_bounds__(256) void k_avgpool4(
    const float* __restrict__ in, float* __restrict__ out)
{
    int idx = blockIdx.x * 256 + threadIdx.x;
    int total = NB * 128 * NPK;
    if (idx >= total) return;
    int pw = idx % 24;
    int t  = idx / 24;
    int ph = t % 24;  t /= 24;
    int c  = t % 128;
    int b  = t / 128;
    const float* ip = in + ((long long)b * 128 + c) * NP + (ph * 4) * WW + pw * 4;
    float4 r0 = *(const float4*)(ip);
    float4 r1 = *(const float4*)(ip + WW);
    float4 r2 = *(const float4*)(ip + 2 * WW);
    float4 r3 = *(const float4*)(ip + 3 * WW);
    float s = ((r0.x + r0.y) + (r0.z + r0.w)) + ((r1.x + r1.y) + (r1.z + r1.w))
            + ((r2.x + r2.y) + (r2.z + r2.w)) + ((r3.x + r3.y) + (r3.z + r3.w));
    out[idx] = s * (1.0f / 16.0f);
}

// ---------------------------------------------------------------------------
extern "C" void kernel_launch(void* const* d_in, const int* in_sizes, int n_in,
                              void* d_out, int out_size, void* d_ws, size_t ws_size,
                              hipStream_t stream)
{
    const float* x      = (const float*)d_in[0];
    const float* qkv_w  = (const float*)d_in[1];
    const float* qkv_b  = (const float*)d_in[2];
    const float* dw_w   = (const float*)d_in[3];
    const float* dw_b   = (const float*)d_in[4];
    const float* am_w1  = (const float*)d_in[5];
    const float* am_b1  = (const float*)d_in[6];
    const float* am_w2  = (const float*)d_in[7];
    const float* am_b2  = (const float*)d_in[8];
    const float* gq_w   = (const float*)d_in[9];
    const float* gq_b   = (const float*)d_in[10];
    const float* gkv_w  = (const float*)d_in[11];
    const float* gkv_b  = (const float*)d_in[12];
    const float* proj_w = (const float*)d_in[13];
    const float* proj_b = (const float*)d_in[14];
    float* out = (float*)d_out;
    char* wsb = (char*)d_ws;

    // byte layout (no overlaps):
    //   [0, 28311552)          t_qkv bf16 (8,192,9216); t_hilo reuses after dwconv
    //   [28311552, 56623104)   t_dw  bf16 (8,192,9216)
    //   [56623104, 66060288)   t_gq  bf16 (8,64,9216)
    //   [66060288, 68419584)   t_pool f32 (8,128,576)
    //   [68419584, 70778880)   t_gkv  f32 (8,128,576)
    //   [70778880, 70926336)   t_pw   packed weights (147KB)
    unsigned short* t_qkv  = (unsigned short*)wsb;
    unsigned short* t_hilo = (unsigned short*)wsb;
    unsigned short* t_dw   = (unsigned short*)(wsb + 28311552);
    unsigned short* t_gq   = (unsigned short*)(wsb + 56623104);
    float*          t_pool = (float*)(wsb + 66060288);
    float*          t_gkv  = (float*)(wsb + 68419584);
    unsigned*       t_pw   = (unsigned*)(wsb + 70778880);

    // 0. pre-pack all conv weights (gq scaled 0.25)
    k_packw<<<dim3((PW_TOTAL + 255) / 256), 256, 0, stream>>>(
        qkv_w, gq_w, gkv_w, am_w1, am_w2, proj_w, t_pw);
    // 1. qkv (bf16) + gq (bf16, *0.25) from one LDS-staged read of x
    k_qkvgq<<<dim3(144, 1, NB), 256, 0, stream>>>(
        x, t_pw, qkv_b, gq_b, t_qkv, t_gq);
    // 2. depthwise 5x5 (bf16 in -> bf16 out)
    k_dwconv5_lds<<<dim3(192, NB), 256, 0, stream>>>(t_qkv, dw_w, dw_b, t_dw, 192);
    // 3. pooled = avgpool4(x)
    k_avgpool4<<<dim3((NB*128*NPK + 255)/256), 256, 0, stream>>>(x, t_pool);
    // 4. gkv = conv1x1(pooled)  f32 out
    k_mfma_conv<128,4,0,0><<<dim3(3,2,NB), 256, 0, stream>>>(
        t_pool, t_pw + PW_GKV, gkv_b, t_gkv, NPK, (long long)128 * NPK, 128);
    // 5+6. merged am (blocks 0..287) + attention (blocks 288..2591)
    k_am_attn<<<dim3(2592), 256, 0, stream>>>(
        t_dw, t_pw, am_b1, am_b2, t_gq, t_gkv, t_hilo);
    // 7. out = conv1x1(hilo bf16, proj_w)  f32 out
    k_mfma_conv<128,4,1,0><<<dim3(36,2,NB), 256, 0, stream>>>(
        t_hilo, t_pw + PW_PROJ, proj_b, out, NP, (long long)128 * NP, 128);
}

// Round 19
// 151.566 us; speedup vs baseline: 1.2394x; 1.0163x over previous
//
#include <hip/hip_runtime.h>
#include <hip/hip_bf16.h>
#include <hip/hip_fp16.h>
#include <cstdint>

static constexpr int NB  = 8;
static constexpr int HH  = 96;
static constexpr int WW  = 96;
static constexpr int NP  = 9216;   // 96*96
static constexpr int NPK = 576;    // 24*24

using bf8 = __attribute__((ext_vector_type(8))) short;
using f4  = __attribute__((ext_vector_type(4))) float;

__device__ __forceinline__ unsigned pack_bf2(float a, float b) {
    __hip_bfloat162 h = __float22bfloat162_rn(make_float2(a, b));
    unsigned u; __builtin_memcpy(&u, &h, 4);
    return u;
}
__device__ __forceinline__ unsigned short f2bfu(float f) {
    __hip_bfloat16 h = __float2bfloat16(f);
    unsigned short u; __builtin_memcpy(&u, &h, 2);
    return u;
}
__device__ __forceinline__ float bf2f(unsigned short u) {
    unsigned v = (unsigned)u << 16;
    float f; __builtin_memcpy(&f, &v, 4);
    return f;
}
__device__ __forceinline__ float bflo(unsigned p) {
    unsigned v = p << 16; float f; __builtin_memcpy(&f, &v, 4); return f;
}
__device__ __forceinline__ float bfhi(unsigned p) {
    unsigned v = p & 0xffff0000u; float f; __builtin_memcpy(&f, &v, 4); return f;
}

// packed-weight segment offsets (uints)
static constexpr int PW_QKV  = 0;       // 192*64
static constexpr int PW_GQ   = 12288;   // 64*64  (scaled 0.25)
static constexpr int PW_GKV  = 16384;   // 128*64
static constexpr int PW_AM1  = 24576;   // 64*32
static constexpr int PW_AM2  = 26624;   // 64*32
static constexpr int PW_PROJ = 28672;   // 128*64
static constexpr int PW_TOTAL= 36864;

// ---------------------------------------------------------------------------
// One-time weight pre-pack (gq segment scaled 0.25).
// ---------------------------------------------------------------------------
__global__ __launch_bounds__(256) void k_packw(
    const float* __restrict__ qkv_w, const float* __restrict__ gq_w,
    const float* __restrict__ gkv_w, const float* __restrict__ am_w1,
    const float* __restrict__ am_w2, const float* __restrict__ proj_w,
    unsigned* __restrict__ pw)
{
    const int idx = blockIdx.x * 256 + threadIdx.x;
    if (idx >= PW_TOTAL) return;
    const float* src; int j2; float sc = 1.0f;
    if (idx < PW_GQ)          { src = qkv_w;  j2 = (idx - PW_QKV) * 2; }
    else if (idx < PW_GKV)    { src = gq_w;   j2 = (idx - PW_GQ) * 2;  sc = 0.25f; }
    else if (idx < PW_AM1)    { src = gkv_w;  j2 = (idx - PW_GKV) * 2; }
    else if (idx < PW_AM2)    { src = am_w1;  j2 = (idx - PW_AM1) * 2; }
    else if (idx < PW_PROJ)   { src = am_w2;  j2 = (idx - PW_AM2) * 2; }
    else                      { src = proj_w; j2 = (idx - PW_PROJ) * 2; }
    pw[idx] = pack_bf2(src[j2] * sc, src[j2 + 1] * sc);
}

// ---------------------------------------------------------------------------
// Fused qkv+gq conv1x1 with LDS-staged x; weights pre-packed. (unchanged)
// ---------------------------------------------------------------------------
__global__ __launch_bounds__(256) void k_qkvgq(
    const float* __restrict__ x, const unsigned* __restrict__ pw,
    const float* __restrict__ qkv_b, const float* __restrict__ gq_b,
    unsigned short* __restrict__ qkv_out,   // bf16 (B,192,NP)
    unsigned short* __restrict__ gq_out)    // bf16 (B,64,NP), pre-scaled 0.25
{
    __shared__ __align__(16) unsigned xl[64 * 64];   // 16KB
    const int tid  = threadIdx.x;
    const int lane = tid & 63, wid = tid >> 6;
    const int quad = blockIdx.x, b = blockIdx.z;
    const int arow = lane & 15, agrp = lane >> 4;

    const float* xb = x + (long long)b * 128 * NP + quad * 64;

#pragma unroll
    for (int it = 0; it < 4; ++it) {
        const int task = tid + 256 * it;
        const int cp = task >> 4, pq = task & 15;
        float4 a = *(const float4*)&xb[(long long)(2 * cp) * NP + pq * 4];
        float4 c = *(const float4*)&xb[(long long)(2 * cp + 1) * NP + pq * 4];
        const int cps = cp ^ ((pq & 7) << 2);
        xl[(pq * 4 + 0) * 64 + cps] = pack_bf2(a.x, c.x);
        xl[(pq * 4 + 1) * 64 + cps] = pack_bf2(a.y, c.y);
        xl[(pq * 4 + 2) * 64 + cps] = pack_bf2(a.z, c.z);
        xl[(pq * 4 + 3) * 64 + cps] = pack_bf2(a.w, c.w);
    }
    __syncthreads();

    uint4 breg[4][4];
#pragma unroll
    for (int kt = 0; kt < 4; ++kt)
#pragma unroll
        for (int i = 0; i < 4; ++i) {
            const int px = arow * 4 + i;
            const int cp = (kt * 16 + agrp * 4) ^ ((arow & 7) << 2);
            breg[kt][i] = *(const uint4*)&xl[px * 64 + cp];
        }

    for (int gi = 0; gi < 4; ++gi) {
        const int grp = wid + gi * 4;
        const bool isgq = grp >= 12;
        const int och = (isgq ? grp - 12 : grp) * 16;
        const unsigned* wseg = pw + (isgq ? PW_GQ : PW_QKV);
        const float* bsrc = isgq ? gq_b : qkv_b;
        const float bsc = isgq ? 0.25f : 1.0f;

        bf8 afr[4];
#pragma unroll
        for (int kt = 0; kt < 4; ++kt) {
            uint4 t = *(const uint4*)&wseg[(och + arow) * 64 + kt * 16 + agrp * 4];
            afr[kt] = __builtin_bit_cast(bf8, t);
        }

        f4 acc[4];
#pragma unroll
        for (int i = 0; i < 4; ++i) acc[i] = (f4){0.f, 0.f, 0.f, 0.f};
#pragma unroll
        for (int kt = 0; kt < 4; ++kt)
#pragma unroll
            for (int i = 0; i < 4; ++i)
                acc[i] = __builtin_amdgcn_mfma_f32_16x16x32_bf16(
                    afr[kt], __builtin_bit_cast(bf8, breg[kt][i]), acc[i], 0, 0, 0);

        unsigned short* ob = isgq ? gq_out : qkv_out;
        const int ostride = isgq ? 64 : 192;
#pragma unroll
        for (int r = 0; r < 4; ++r) {
            const int o = och + agrp * 4 + r;
            const float bs = bsrc[o] * bsc;
            const float v0 = acc[0][r] + bs, v1 = acc[1][r] + bs;
            const float v2 = acc[2][r] + bs, v3 = acc[3][r] + bs;
            *(uint2*)&ob[((long long)b * ostride + o) * NP + quad * 64 + arow * 4] =
                make_uint2(pack_bf2(v0, v1), pack_bf2(v2, v3));
        }
    }
}

// ---------------------------------------------------------------------------
// MFMA conv1x1 (generic; gkv f32->f32 and proj bf16->f32); weights pre-packed.
// ---------------------------------------------------------------------------
template<int C, int OT, int INBF, int OUTBF>
__global__ __launch_bounds__(256) void k_mfma_conv(
    const void* __restrict__ in0v, const unsigned* __restrict__ pw,
    const float* __restrict__ bias, void* __restrict__ outv,
    int np, long long ibs, int storeO)
{
    constexpr int KT = C / 32;
    const int tid  = threadIdx.x;
    const int lane = tid & 63, wid = tid >> 6;
    const int b    = blockIdx.z;
    const int obq  = blockIdx.y * (OT * 16);
    const int arow = lane & 15, agrp = lane >> 4;
    const int nquad = np >> 6;

    bf8 afr[OT][KT];
#pragma unroll
    for (int ot = 0; ot < OT; ++ot)
#pragma unroll
        for (int kt = 0; kt < KT; ++kt) {
            uint4 t = *(const uint4*)&pw[(obq + ot * 16 + arow) * (C / 2) + kt * 16 + agrp * 4];
            afr[ot][kt] = __builtin_bit_cast(bf8, t);
        }

    const float*          x0f = (const float*)in0v          + (long long)b * (INBF ? 0 : ibs);
    const unsigned short* x0h = (const unsigned short*)in0v + (long long)b * (INBF ? ibs : 0);

    const int quad = blockIdx.x * 4 + wid;
    if (quad >= nquad) return;
    const int p0 = quad * 64 + arow * 4;

    f4 acc[4][OT];
#pragma unroll
    for (int i = 0; i < 4; ++i)
#pragma unroll
        for (int ot = 0; ot < OT; ++ot) acc[i][ot] = (f4){0.f, 0.f, 0.f, 0.f};

#pragma unroll
    for (int kt = 0; kt < KT; ++kt) {
        const long long cbase = kt * 32 + agrp * 8;
        int uu[4][4];
#pragma unroll
        for (int jj = 0; jj < 4; ++jj) {
            if (INBF == 0) {
                float4 a0 = *(const float4*)&x0f[(cbase + 2 * jj) * np + p0];
                float4 a1 = *(const float4*)&x0f[(cbase + 2 * jj + 1) * np + p0];
                uu[0][jj] = (int)pack_bf2(a0.x, a1.x);
                uu[1][jj] = (int)pack_bf2(a0.y, a1.y);
                uu[2][jj] = (int)pack_bf2(a0.z, a1.z);
                uu[3][jj] = (int)pack_bf2(a0.w, a1.w);
            } else {
                ushort4 a0 = *(const ushort4*)&x0h[(cbase + 2 * jj) * np + p0];
                ushort4 a1 = *(const ushort4*)&x0h[(cbase + 2 * jj + 1) * np + p0];
                uu[0][jj] = (int)((unsigned)a0.x | ((unsigned)a1.x << 16));
                uu[1][jj] = (int)((unsigned)a0.y | ((unsigned)a1.y << 16));
                uu[2][jj] = (int)((unsigned)a0.z | ((unsigned)a1.z << 16));
                uu[3][jj] = (int)((unsigned)a0.w | ((unsigned)a1.w << 16));
            }
        }
#pragma unroll
        for (int i = 0; i < 4; ++i) {
            int4 ti = {uu[i][0], uu[i][1], uu[i][2], uu[i][3]};
            bf8 bfr = __builtin_bit_cast(bf8, ti);
#pragma unroll
            for (int ot = 0; ot < OT; ++ot)
                acc[i][ot] = __builtin_amdgcn_mfma_f32_16x16x32_bf16(afr[ot][kt], bfr, acc[i][ot], 0, 0, 0);
        }
    }

#pragma unroll
    for (int ot = 0; ot < OT; ++ot) {
#pragma unroll
        for (int r = 0; r < 4; ++r) {
            const int o = obq + ot * 16 + agrp * 4 + r;
            const float bs = bias[o];
            float4 v;
            v.x = acc[0][ot][r] + bs;
            v.y = acc[1][ot][r] + bs;
            v.z = acc[2][ot][r] + bs;
            v.w = acc[3][ot][r] + bs;
            const long long idx = ((long long)b * storeO + o) * np + p0;
            if (OUTBF == 0) {
                *(float4*)&((float*)outv)[idx] = v;
            } else {
                *(uint2*)&((unsigned short*)outv)[idx] =
                    make_uint2(pack_bf2(v.x, v.y), pack_bf2(v.z, v.w));
            }
        }
    }
}

// ---------------------------------------------------------------------------
// Merged am + attention kernel (r18, unchanged; verified).
// ---------------------------------------------------------------------------
__global__ __launch_bounds__(256) void k_am_attn(
    const unsigned short* __restrict__ dw, const unsigned* __restrict__ pw,
    const float* __restrict__ b1v, const float* __restrict__ b2v,
    const unsigned short* __restrict__ q, const float* __restrict__ kv,
    unsigned short* __restrict__ hilo)
{
    __shared__ __align__(16) char smem[53760];
    const int bid = blockIdx.x;
    const int tid = threadIdx.x;
    const int lane = tid & 63, wid = tid >> 6;

    if (bid < 288) {
        // ================= am path =================
        uint2* abuf = (uint2*)smem;
        const int b = bid / 36;
        const int arow = lane & 15, agrp = lane >> 4;

        bf8 afr1[4][2], afr2[4][2];
#pragma unroll
        for (int ot = 0; ot < 4; ++ot)
#pragma unroll
            for (int kt = 0; kt < 2; ++kt) {
                uint4 t1 = *(const uint4*)&pw[PW_AM1 + (ot * 16 + arow) * 32 + kt * 16 + agrp * 4];
                uint4 t2 = *(const uint4*)&pw[PW_AM2 + (ot * 16 + arow) * 32 + kt * 16 + agrp * 4];
                afr1[ot][kt] = __builtin_bit_cast(bf8, t1);
                afr2[ot][kt] = __builtin_bit_cast(bf8, t2);
            }

        const unsigned short* xq = dw + (long long)b * (192ll * NP);
        const unsigned short* xk = xq + 64ll * NP;
        const unsigned short* xv = xq + 128ll * NP;

        const int quad = (bid % 36) * 4 + wid;
        const int p0 = quad * 64 + arow * 4;

        f4 acc1[4][4];
#pragma unroll
        for (int i = 0; i < 4; ++i)
#pragma unroll
            for (int ot = 0; ot < 4; ++ot) acc1[i][ot] = (f4){0.f, 0.f, 0.f, 0.f};

#pragma unroll
        for (int kt = 0; kt < 2; ++kt) {
            const long long cbase = kt * 32 + agrp * 8;
            int uu[4][4];
#pragma unroll
            for (int jj = 0; jj < 4; ++jj) {
                ushort4 a0 = *(const ushort4*)&xq[(cbase + 2 * jj) * NP + p0];
                ushort4 a1 = *(const ushort4*)&xq[(cbase + 2 * jj + 1) * NP + p0];
                ushort4 y0 = *(const ushort4*)&xk[(cbase + 2 * jj) * NP + p0];
                ushort4 y1 = *(const ushort4*)&xk[(cbase + 2 * jj + 1) * NP + p0];
                uu[0][jj] = (int)pack_bf2(bf2f(a0.x) * bf2f(y0.x), bf2f(a1.x) * bf2f(y1.x));
                uu[1][jj] = (int)pack_bf2(bf2f(a0.y) * bf2f(y0.y), bf2f(a1.y) * bf2f(y1.y));
                uu[2][jj] = (int)pack_bf2(bf2f(a0.z) * bf2f(y0.z), bf2f(a1.z) * bf2f(y1.z));
                uu[3][jj] = (int)pack_bf2(bf2f(a0.w) * bf2f(y0.w), bf2f(a1.w) * bf2f(y1.w));
            }
#pragma unroll
            for (int i = 0; i < 4; ++i) {
                int4 ti = {uu[i][0], uu[i][1], uu[i][2], uu[i][3]};
                bf8 bfr = __builtin_bit_cast(bf8, ti);
#pragma unroll
                for (int ot = 0; ot < 4; ++ot)
                    acc1[i][ot] = __builtin_amdgcn_mfma_f32_16x16x32_bf16(afr1[ot][kt], bfr, acc1[i][ot], 0, 0, 0);
            }
        }

#pragma unroll
        for (int i = 0; i < 4; ++i)
#pragma unroll
            for (int ot = 0; ot < 4; ++ot) {
                const int ch0 = ot * 16 + agrp * 4;
                float v0 = acc1[i][ot][0] + b1v[ch0 + 0];
                float v1 = acc1[i][ot][1] + b1v[ch0 + 1];
                float v2 = acc1[i][ot][2] + b1v[ch0 + 2];
                float v3 = acc1[i][ot][3] + b1v[ch0 + 3];
                v0 = v0 / (1.f + __expf(-v0));
                v1 = v1 / (1.f + __expf(-v1));
                v2 = v2 / (1.f + __expf(-v2));
                v3 = v3 / (1.f + __expf(-v3));
                const int c2 = ot * 4 + agrp;
                abuf[wid * 1024 + (arow * 4 + i) * 16 + (c2 ^ arow)] =
                    make_uint2(pack_bf2(v0, v1), pack_bf2(v2, v3));
            }

        f4 acc2[4][4];
#pragma unroll
        for (int i = 0; i < 4; ++i)
#pragma unroll
            for (int ot = 0; ot < 4; ++ot) acc2[i][ot] = (f4){0.f, 0.f, 0.f, 0.f};

#pragma unroll
        for (int kt = 0; kt < 2; ++kt) {
            const int bc2 = kt * 8 + agrp * 2;
#pragma unroll
            for (int i = 0; i < 4; ++i) {
                const uint2 rA = abuf[wid * 1024 + (arow * 4 + i) * 16 + (bc2 ^ arow)];
                const uint2 rB = abuf[wid * 1024 + (arow * 4 + i) * 16 + ((bc2 + 1) ^ arow)];
                int4 ti = make_int4((int)rA.x, (int)rA.y, (int)rB.x, (int)rB.y);
                bf8 bfr = __builtin_bit_cast(bf8, ti);
#pragma unroll
                for (int ot = 0; ot < 4; ++ot)
                    acc2[i][ot] = __builtin_amdgcn_mfma_f32_16x16x32_bf16(afr2[ot][kt], bfr, acc2[i][ot], 0, 0, 0);
            }
        }

#pragma unroll
        for (int ot = 0; ot < 4; ++ot) {
#pragma unroll
            for (int r = 0; r < 4; ++r) {
                const int o = ot * 16 + agrp * 4 + r;
                const float bs = b2v[o];
                ushort4 vv4 = *(const ushort4*)&xv[(long long)o * NP + p0];
                float h0 = tanhf((acc2[0][ot][r] + bs) * 0.25f) * bf2f(vv4.x);
                float h1 = tanhf((acc2[1][ot][r] + bs) * 0.25f) * bf2f(vv4.y);
                float h2 = tanhf((acc2[2][ot][r] + bs) * 0.25f) * bf2f(vv4.z);
                float h3 = tanhf((acc2[3][ot][r] + bs) * 0.25f) * bf2f(vv4.w);
                *(uint2*)&hilo[((long long)b * 128 + o) * NP + p0] =
                    make_uint2(pack_bf2(h0, h1), pack_bf2(h2, h3));
            }
        }
        return;
    }

    // ================= attn path (r12-exact logic) =================
    int4*  klds4 = (int4*)smem;
    int4*  zlds4 = (int4*)(smem + 18432);
    int4*  vlds4 = (int4*)(smem + 18944);
    uint2* elds2 = (uint2*)(smem + 37376);

    const int flat = bid - 288;
    const int bx = flat % 72, bh = flat / 72;
    const int g = lane >> 4, qi = lane & 15;
    const int b = bh >> 2, h = bh & 3;

    const float* kbase = kv + ((long long)b * 128 + h * 16) * NPK;
    const float* vbase = kv + ((long long)b * 128 + 64 + h * 16) * NPK;

    for (int i = tid; i < 1152; i += 256) {
        const int key = i >> 1, dg = i & 1;
        const float* kp = kbase + (long long)(dg * 8) * NPK + key;
        int4 t;
        t.x = (int)pack_bf2(kp[0],       kp[NPK]);
        t.y = (int)pack_bf2(kp[2 * NPK], kp[3 * NPK]);
        t.z = (int)pack_bf2(kp[4 * NPK], kp[5 * NPK]);
        t.w = (int)pack_bf2(kp[6 * NPK], kp[7 * NPK]);
        klds4[(key >> 4) * 32 + dg * 16 + (key & 15)] = t;
    }
    for (int i = tid; i < 1152; i += 256) {
        const int t = i >> 6, l = i & 63;
        const float* vp = vbase + (long long)(l & 15) * NPK + t * 32 + (l >> 4) * 8;
        float4 a = *(const float4*)vp;
        float4 c = *(const float4*)(vp + 4);
        int4 tt;
        tt.x = (int)pack_bf2(a.x, a.y);
        tt.y = (int)pack_bf2(a.z, a.w);
        tt.z = (int)pack_bf2(c.x, c.y);
        tt.w = (int)pack_bf2(c.z, c.w);
        vlds4[i] = tt;
    }
    if (tid < 32) zlds4[tid] = make_int4(0, 0, 0, 0);
    __syncthreads();

    const int q0 = (bx * 4 + wid) * 32;
    const unsigned short* qcol = q + ((long long)b * 64 + h * 16) * NP + q0 + qi;
    int4 qv[2] = { make_int4(0, 0, 0, 0), make_int4(0, 0, 0, 0) };
    if (g < 2) {
#pragma unroll
        for (int s = 0; s < 2; ++s) {
            const unsigned short* qp = qcol + s * 16 + (long long)(g * 8) * NP;
            qv[s].x = (int)((unsigned)qp[0]          | ((unsigned)qp[(long long)NP]     << 16));
            qv[s].y = (int)((unsigned)qp[2ll * NP]   | ((unsigned)qp[3ll * NP]          << 16));
            qv[s].z = (int)((unsigned)qp[4ll * NP]   | ((unsigned)qp[5ll * NP]          << 16));
            qv[s].w = (int)((unsigned)qp[6ll * NP]   | ((unsigned)qp[7ll * NP]          << 16));
        }
    }

    f4 accp[2] = { (f4){0.f, 0.f, 0.f, 0.f}, (f4){0.f, 0.f, 0.f, 0.f} };
    float den[2] = { 0.f, 0.f };

    auto QKEXP = [&](int k2, int buf) {
#pragma unroll
        for (int tp = 0; tp < 2; ++tp) {
            const int4 kf = (lane < 32) ? klds4[(k2 * 2 + tp) * 32 + lane]
                                        : zlds4[lane & 31];
            const bf8 ka = __builtin_bit_cast(bf8, kf);
#pragma unroll
            for (int s = 0; s < 2; ++s) {
                f4 sa = __builtin_amdgcn_mfma_f32_16x16x32_bf16(
                    ka, __builtin_bit_cast(bf8, qv[s]), (f4){0.f, 0.f, 0.f, 0.f}, 0, 0, 0);
                const float e0 = __expf(sa[0]), e1 = __expf(sa[1]);
                const float e2 = __expf(sa[2]), e3 = __expf(sa[3]);
                den[s] += (e0 + e1) + (e2 + e3);
                elds2[buf * 1024 + wid * 256 + s * 128 + tp * 64 + g * 16 + qi] =
                    make_uint2(pack_bf2(e0, e1), pack_bf2(e2, e3));
            }
        }
    };
    auto PV = [&](int k2, int buf) {
        const bf8 va = __builtin_bit_cast(bf8, vlds4[k2 * 64 + lane]);
#pragma unroll
        for (int s = 0; s < 2; ++s) {
            const int base = buf * 1024 + wid * 256 + s * 128 + (g >> 1) * 64 + (g & 1) * 32 + qi;
            const uint2 r0 = elds2[base];
            const uint2 r1 = elds2[base + 16];
            int4 ti = make_int4((int)r0.x, (int)r0.y, (int)r1.x, (int)r1.y);
            accp[s] = __builtin_amdgcn_mfma_f32_16x16x32_bf16(
                va, __builtin_bit_cast(bf8, ti), accp[s], 0, 0, 0);
        }
    };

    QKEXP(0, 0);
    for (int k2 = 0; k2 < 17; ++k2) {
        QKEXP(k2 + 1, (k2 + 1) & 1);
        PV(k2, k2 & 1);
    }
    PV(17, 1);

#pragma unroll
    for (int s = 0; s < 2; ++s) {
        float d0 = den[s];
        d0 += __shfl_xor(d0, 16, 64);
        d0 += __shfl_xor(d0, 32, 64);
        const float inv = 1.0f / d0;
        unsigned short* op = hilo + ((long long)b * 128 + 64 + h * 16 + g * 4) * NP + q0 + s * 16 + qi;
#pragma unroll
        for (int r = 0; r < 4; ++r)
            op[(long long)r * NP] = f2bfu(accp[s][r] * inv);
    }
}

// ---------------------------------------------------------------------------
// depthwise 5x5, pad 2 — row-tiled LDS staging (3 tiles of 32 output rows;
// stage 36 rows incl. zero-filled halo = 13.8KB -> 8 blocks/CU).
// Arithmetic identical to full-image version (w*0 for halo == skipped taps).
// ---------------------------------------------------------------------------
__global__ __launch_bounds__(256) void k_dwconv5_lds(
    const unsigned short* __restrict__ in, const float* __restrict__ w,
    const float* __restrict__ bias, unsigned short* __restrict__ out, int ch_total)
{
    __shared__ __align__(16) float img[36 * WW];   // 13824 B
    const int tid = threadIdx.x;
    const int ch  = blockIdx.x;
    const int rt  = blockIdx.y;      // row tile 0..2
    const int b   = blockIdx.z;
    const unsigned short* ip = in + ((long long)b * ch_total + ch) * NP;

    const int gr0 = rt * 32 - 2;     // global row of img row 0
    for (int idx = tid; idx < 864; idx += 256) {     // 36 rows * 24 quads
        const int rr = idx / 24, c4 = (idx - rr * 24) * 4;
        const int gr = gr0 + rr;
        float4 f;
        if (gr >= 0 && gr < HH) {
            const uint2 rv = *(const uint2*)&ip[gr * WW + c4];
            f.x = bflo(rv.x); f.y = bfhi(rv.x);
            f.z = bflo(rv.y); f.w = bfhi(rv.y);
        } else {
            f = make_float4(0.f, 0.f, 0.f, 0.f);
        }
        *(float4*)&img[rr * WW + c4] = f;
    }
    __syncthreads();

    const float* wp = w + ch * 25;
    float wr[25];
#pragma unroll
    for (int i = 0; i < 25; ++i) wr[i] = wp[i];
    const float bs = bias[ch];

    unsigned short* op = out + ((long long)b * ch_total + ch) * NP + rt * 32 * WW;

#pragma unroll
    for (int j = 0; j < 3; ++j) {
        const int q  = tid + 256 * j;        // 0..767
        const int yl = q / 24;               // 0..31 (output row within tile)
        const int x4 = (q - yl * 24) * 4;
        float o0 = bs, o1 = bs, o2 = bs, o3 = bs;
#pragma unroll
        for (int ky = 0; ky < 5; ++ky) {
            const float* row = &img[(yl + ky) * WW + x4];   // halo rows are zero
            float4 mid = *(const float4*)row;
            float4 lf  = (x4 >= 4)      ? *(const float4*)(row - 4)
                                        : make_float4(0.f, 0.f, 0.f, 0.f);
            float4 rtv = (x4 + 4 < WW)  ? *(const float4*)(row + 4)
                                        : make_float4(0.f, 0.f, 0.f, 0.f);
            const float f0 = lf.z,  f1 = lf.w;
            const float f2 = mid.x, f3 = mid.y, f4v = mid.z, f5 = mid.w;
            const float f6 = rtv.x, f7 = rtv.y;
            const float w0 = wr[ky * 5 + 0], w1 = wr[ky * 5 + 1],
                        w2 = wr[ky * 5 + 2], w3 = wr[ky * 5 + 3],
                        w4 = wr[ky * 5 + 4];
            o0 = fmaf(w0, f0, o0); o0 = fmaf(w1, f1, o0); o0 = fmaf(w2, f2, o0);
            o0 = fmaf(w3, f3, o0); o0 = fmaf(w4, f4v, o0);
            o1 = fmaf(w0, f1, o1); o1 = fmaf(w1, f2, o1); o1 = fmaf(w2, f3, o1);
            o1 = fmaf(w3, f4v, o1); o1 = fmaf(w4, f5, o1);
            o2 = fmaf(w0, f2, o2); o2 = fmaf(w1, f3, o2); o2 = fmaf(w2, f4v, o2);
            o2 = fmaf(w3, f5, o2); o2 = fmaf(w4, f6, o2);
            o3 = fmaf(w0, f3, o3); o3 = fmaf(w1, f4v, o3); o3 = fmaf(w2, f5, o3);
            o3 = fmaf(w3, f6, o3); o3 = fmaf(w4, f7, o3);
        }
        *(uint2*)&op[yl * WW + x4] = make_uint2(pack_bf2(o0, o1), pack_bf2(o2, o3));
    }
}

// ---------------------------------------------------------------------------
// 4x4 average pool — float4 loads.  (unchanged)
// ---------------------------------------------------------------------------
__global__ __launch_bounds__(256) void k_avgpool4(
    const float* __restrict__ in, float* __restrict__ out)
{
    int idx = blockIdx.x * 256 + threadIdx.x;
    int total = NB * 128 * NPK;
    if (idx >= total) return;
    int pw = idx % 24;
    int t  = idx / 24;
    int ph = t % 24;  t /= 24;
    int c  = t % 128;
    int b  = t / 128;
    const float* ip = in + ((long long)b * 128 + c) * NP + (ph * 4) * WW + pw * 4;
    float4 r0 = *(const float4*)(ip);
    float4 r1 = *(const float4*)(ip + WW);
    float4 r2 = *(const float4*)(ip + 2 * WW);
    float4 r3 = *(const float4*)(ip + 3 * WW);
    float s = ((r0.x + r0.y) + (r0.z + r0.w)) + ((r1.x + r1.y) + (r1.z + r1.w))
            + ((r2.x + r2.y) + (r2.z + r2.w)) + ((r3.x + r3.y) + (r3.z + r3.w));
    out[idx] = s * (1.0f / 16.0f);
}

// ---------------------------------------------------------------------------
extern "C" void kernel_launch(void* const* d_in, const int* in_sizes, int n_in,
                              void* d_out, int out_size, void* d_ws, size_t ws_size,
                              hipStream_t stream)
{
    const float* x      = (const float*)d_in[0];
    const float* qkv_w  = (const float*)d_in[1];
    const float* qkv_b  = (const float*)d_in[2];
    const float* dw_w   = (const float*)d_in[3];
    const float* dw_b   = (const float*)d_in[4];
    const float* am_w1  = (const float*)d_in[5];
    const float* am_b1  = (const float*)d_in[6];
    const float* am_w2  = (const float*)d_in[7];
    const float* am_b2  = (const float*)d_in[8];
    const float* gq_w   = (const float*)d_in[9];
    const float* gq_b   = (const float*)d_in[10];
    const float* gkv_w  = (const float*)d_in[11];
    const float* gkv_b  = (const float*)d_in[12];
    const float* proj_w = (const float*)d_in[13];
    const float* proj_b = (const float*)d_in[14];
    float* out = (float*)d_out;
    char* wsb = (char*)d_ws;

    // byte layout (no overlaps):
    //   [0, 28311552)          t_qkv bf16 (8,192,9216); t_hilo reuses after dwconv
    //   [28311552, 56623104)   t_dw  bf16 (8,192,9216)
    //   [56623104, 66060288)   t_gq  bf16 (8,64,9216)
    //   [66060288, 68419584)   t_pool f32 (8,128,576)
    //   [68419584, 70778880)   t_gkv  f32 (8,128,576)
    //   [70778880, 70926336)   t_pw   packed weights (147KB)
    unsigned short* t_qkv  = (unsigned short*)wsb;
    unsigned short* t_hilo = (unsigned short*)wsb;
    unsigned short* t_dw   = (unsigned short*)(wsb + 28311552);
    unsigned short* t_gq   = (unsigned short*)(wsb + 56623104);
    float*          t_pool = (float*)(wsb + 66060288);
    float*          t_gkv  = (float*)(wsb + 68419584);
    unsigned*       t_pw   = (unsigned*)(wsb + 70778880);

    // 0. pre-pack all conv weights (gq scaled 0.25)
    k_packw<<<dim3((PW_TOTAL + 255) / 256), 256, 0, stream>>>(
        qkv_w, gq_w, gkv_w, am_w1, am_w2, proj_w, t_pw);
    // 1. qkv (bf16) + gq (bf16, *0.25) from one LDS-staged read of x
    k_qkvgq<<<dim3(144, 1, NB), 256, 0, stream>>>(
        x, t_pw, qkv_b, gq_b, t_qkv, t_gq);
    // 2. depthwise 5x5 (bf16 in -> bf16 out), row-tiled
    k_dwconv5_lds<<<dim3(192, 3, NB), 256, 0, stream>>>(t_qkv, dw_w, dw_b, t_dw, 192);
    // 3. pooled = avgpool4(x)
    k_avgpool4<<<dim3((NB*128*NPK + 255)/256), 256, 0, stream>>>(x, t_pool);
    // 4. gkv = conv1x1(pooled)  f32 out
    k_mfma_conv<128,4,0,0><<<dim3(3,2,NB), 256, 0, stream>>>(
        t_pool, t_pw + PW_GKV, gkv_b, t_gkv, NPK, (long long)128 * NPK, 128);
    // 5+6. merged am (blocks 0..287) + attention (blocks 288..2591)
    k_am_attn<<<dim3(2592), 256, 0, stream>>>(
        t_dw, t_pw, am_b1, am_b2, t_gq, t_gkv, t_hilo);
    // 7. out = conv1x1(hilo bf16, proj_w)  f32 out
    k_mfma_conv<128,4,1,0><<<dim3(36,2,NB), 256, 0, stream>>>(
        t_hilo, t_pw + PW_PROJ, proj_b, out, NP, (long long)128 * NP, 128);
}

// Round 20
// 144.296 us; speedup vs baseline: 1.3018x; 1.0504x over previous
//
#include <hip/hip_runtime.h>
#include <hip/hip_bf16.h>
#include <hip/hip_fp16.h>
#include <cstdint>

static constexpr int NB  = 8;
static constexpr int HH  = 96;
static constexpr int WW  = 96;
static constexpr int NP  = 9216;   // 96*96
static constexpr int NPK = 576;    // 24*24

using bf8 = __attribute__((ext_vector_type(8))) short;
using f4  = __attribute__((ext_vector_type(4))) float;

__device__ __forceinline__ unsigned pack_bf2(float a, float b) {
    __hip_bfloat162 h = __float22bfloat162_rn(make_float2(a, b));
    unsigned u; __builtin_memcpy(&u, &h, 4);
    return u;
}
__device__ __forceinline__ unsigned short f2bfu(float f) {
    __hip_bfloat16 h = __float2bfloat16(f);
    unsigned short u; __builtin_memcpy(&u, &h, 2);
    return u;
}
__device__ __forceinline__ float bf2f(unsigned short u) {
    unsigned v = (unsigned)u << 16;
    float f; __builtin_memcpy(&f, &v, 4);
    return f;
}
__device__ __forceinline__ float bflo(unsigned p) {
    unsigned v = p << 16; float f; __builtin_memcpy(&f, &v, 4); return f;
}
__device__ __forceinline__ float bfhi(unsigned p) {
    unsigned v = p & 0xffff0000u; float f; __builtin_memcpy(&f, &v, 4); return f;
}

// packed-weight segment offsets (uints)
static constexpr int PW_QKV  = 0;       // 192*64
static constexpr int PW_GQ   = 12288;   // 64*64  (scaled 0.25)
static constexpr int PW_GKV  = 16384;   // 128*64
static constexpr int PW_AM1  = 24576;   // 64*32
static constexpr int PW_AM2  = 26624;   // 64*32
static constexpr int PW_PROJ = 28672;   // 128*64
static constexpr int PW_TOTAL= 36864;

// ---------------------------------------------------------------------------
// One-time weight pre-pack (gq segment scaled 0.25).
// ---------------------------------------------------------------------------
__global__ __launch_bounds__(256) void k_packw(
    const float* __restrict__ qkv_w, const float* __restrict__ gq_w,
    const float* __restrict__ gkv_w, const float* __restrict__ am_w1,
    const float* __restrict__ am_w2, const float* __restrict__ proj_w,
    unsigned* __restrict__ pw)
{
    const int idx = blockIdx.x * 256 + threadIdx.x;
    if (idx >= PW_TOTAL) return;
    const float* src; int j2; float sc = 1.0f;
    if (idx < PW_GQ)          { src = qkv_w;  j2 = (idx - PW_QKV) * 2; }
    else if (idx < PW_GKV)    { src = gq_w;   j2 = (idx - PW_GQ) * 2;  sc = 0.25f; }
    else if (idx < PW_AM1)    { src = gkv_w;  j2 = (idx - PW_GKV) * 2; }
    else if (idx < PW_AM2)    { src = am_w1;  j2 = (idx - PW_AM1) * 2; }
    else if (idx < PW_PROJ)   { src = am_w2;  j2 = (idx - PW_AM2) * 2; }
    else                      { src = proj_w; j2 = (idx - PW_PROJ) * 2; }
    pw[idx] = pack_bf2(src[j2] * sc, src[j2 + 1] * sc);
}

// ---------------------------------------------------------------------------
// Fused qkv+gq conv1x1 with LDS-staged x; weights pre-packed. (unchanged)
// ---------------------------------------------------------------------------
__global__ __launch_bounds__(256) void k_qkvgq(
    const float* __restrict__ x, const unsigned* __restrict__ pw,
    const float* __restrict__ qkv_b, const float* __restrict__ gq_b,
    unsigned short* __restrict__ qkv_out,   // bf16 (B,192,NP)
    unsigned short* __restrict__ gq_out)    // bf16 (B,64,NP), pre-scaled 0.25
{
    __shared__ __align__(16) unsigned xl[64 * 64];   // 16KB
    const int tid  = threadIdx.x;
    const int lane = tid & 63, wid = tid >> 6;
    const int quad = blockIdx.x, b = blockIdx.z;
    const int arow = lane & 15, agrp = lane >> 4;

    const float* xb = x + (long long)b * 128 * NP + quad * 64;

#pragma unroll
    for (int it = 0; it < 4; ++it) {
        const int task = tid + 256 * it;
        const int cp = task >> 4, pq = task & 15;
        float4 a = *(const float4*)&xb[(long long)(2 * cp) * NP + pq * 4];
        float4 c = *(const float4*)&xb[(long long)(2 * cp + 1) * NP + pq * 4];
        const int cps = cp ^ ((pq & 7) << 2);
        xl[(pq * 4 + 0) * 64 + cps] = pack_bf2(a.x, c.x);
        xl[(pq * 4 + 1) * 64 + cps] = pack_bf2(a.y, c.y);
        xl[(pq * 4 + 2) * 64 + cps] = pack_bf2(a.z, c.z);
        xl[(pq * 4 + 3) * 64 + cps] = pack_bf2(a.w, c.w);
    }
    __syncthreads();

    uint4 breg[4][4];
#pragma unroll
    for (int kt = 0; kt < 4; ++kt)
#pragma unroll
        for (int i = 0; i < 4; ++i) {
            const int px = arow * 4 + i;
            const int cp = (kt * 16 + agrp * 4) ^ ((arow & 7) << 2);
            breg[kt][i] = *(const uint4*)&xl[px * 64 + cp];
        }

    for (int gi = 0; gi < 4; ++gi) {
        const int grp = wid + gi * 4;
        const bool isgq = grp >= 12;
        const int och = (isgq ? grp - 12 : grp) * 16;
        const unsigned* wseg = pw + (isgq ? PW_GQ : PW_QKV);
        const float* bsrc = isgq ? gq_b : qkv_b;
        const float bsc = isgq ? 0.25f : 1.0f;

        bf8 afr[4];
#pragma unroll
        for (int kt = 0; kt < 4; ++kt) {
            uint4 t = *(const uint4*)&wseg[(och + arow) * 64 + kt * 16 + agrp * 4];
            afr[kt] = __builtin_bit_cast(bf8, t);
        }

        f4 acc[4];
#pragma unroll
        for (int i = 0; i < 4; ++i) acc[i] = (f4){0.f, 0.f, 0.f, 0.f};
#pragma unroll
        for (int kt = 0; kt < 4; ++kt)
#pragma unroll
            for (int i = 0; i < 4; ++i)
                acc[i] = __builtin_amdgcn_mfma_f32_16x16x32_bf16(
                    afr[kt], __builtin_bit_cast(bf8, breg[kt][i]), acc[i], 0, 0, 0);

        unsigned short* ob = isgq ? gq_out : qkv_out;
        const int ostride = isgq ? 64 : 192;
#pragma unroll
        for (int r = 0; r < 4; ++r) {
            const int o = och + agrp * 4 + r;
            const float bs = bsrc[o] * bsc;
            const float v0 = acc[0][r] + bs, v1 = acc[1][r] + bs;
            const float v2 = acc[2][r] + bs, v3 = acc[3][r] + bs;
            *(uint2*)&ob[((long long)b * ostride + o) * NP + quad * 64 + arow * 4] =
                make_uint2(pack_bf2(v0, v1), pack_bf2(v2, v3));
        }
    }
}

// ---------------------------------------------------------------------------
// MFMA conv1x1 (generic; gkv f32->f32 and proj bf16->f32); weights pre-packed.
// ---------------------------------------------------------------------------
template<int C, int OT, int INBF, int OUTBF>
__global__ __launch_bounds__(256) void k_mfma_conv(
    const void* __restrict__ in0v, const unsigned* __restrict__ pw,
    const float* __restrict__ bias, void* __restrict__ outv,
    int np, long long ibs, int storeO)
{
    constexpr int KT = C / 32;
    const int tid  = threadIdx.x;
    const int lane = tid & 63, wid = tid >> 6;
    const int b    = blockIdx.z;
    const int obq  = blockIdx.y * (OT * 16);
    const int arow = lane & 15, agrp = lane >> 4;
    const int nquad = np >> 6;

    bf8 afr[OT][KT];
#pragma unroll
    for (int ot = 0; ot < OT; ++ot)
#pragma unroll
        for (int kt = 0; kt < KT; ++kt) {
            uint4 t = *(const uint4*)&pw[(obq + ot * 16 + arow) * (C / 2) + kt * 16 + agrp * 4];
            afr[ot][kt] = __builtin_bit_cast(bf8, t);
        }

    const float*          x0f = (const float*)in0v          + (long long)b * (INBF ? 0 : ibs);
    const unsigned short* x0h = (const unsigned short*)in0v + (long long)b * (INBF ? ibs : 0);

    const int quad = blockIdx.x * 4 + wid;
    if (quad >= nquad) return;
    const int p0 = quad * 64 + arow * 4;

    f4 acc[4][OT];
#pragma unroll
    for (int i = 0; i < 4; ++i)
#pragma unroll
        for (int ot = 0; ot < OT; ++ot) acc[i][ot] = (f4){0.f, 0.f, 0.f, 0.f};

#pragma unroll
    for (int kt = 0; kt < KT; ++kt) {
        const long long cbase = kt * 32 + agrp * 8;
        int uu[4][4];
#pragma unroll
        for (int jj = 0; jj < 4; ++jj) {
            if (INBF == 0) {
                float4 a0 = *(const float4*)&x0f[(cbase + 2 * jj) * np + p0];
                float4 a1 = *(const float4*)&x0f[(cbase + 2 * jj + 1) * np + p0];
                uu[0][jj] = (int)pack_bf2(a0.x, a1.x);
                uu[1][jj] = (int)pack_bf2(a0.y, a1.y);
                uu[2][jj] = (int)pack_bf2(a0.z, a1.z);
                uu[3][jj] = (int)pack_bf2(a0.w, a1.w);
            } else {
                ushort4 a0 = *(const ushort4*)&x0h[(cbase + 2 * jj) * np + p0];
                ushort4 a1 = *(const ushort4*)&x0h[(cbase + 2 * jj + 1) * np + p0];
                uu[0][jj] = (int)((unsigned)a0.x | ((unsigned)a1.x << 16));
                uu[1][jj] = (int)((unsigned)a0.y | ((unsigned)a1.y << 16));
                uu[2][jj] = (int)((unsigned)a0.z | ((unsigned)a1.z << 16));
                uu[3][jj] = (int)((unsigned)a0.w | ((unsigned)a1.w << 16));
            }
        }
#pragma unroll
        for (int i = 0; i < 4; ++i) {
            int4 ti = {uu[i][0], uu[i][1], uu[i][2], uu[i][3]};
            bf8 bfr = __builtin_bit_cast(bf8, ti);
#pragma unroll
            for (int ot = 0; ot < OT; ++ot)
                acc[i][ot] = __builtin_amdgcn_mfma_f32_16x16x32_bf16(afr[ot][kt], bfr, acc[i][ot], 0, 0, 0);
        }
    }

#pragma unroll
    for (int ot = 0; ot < OT; ++ot) {
#pragma unroll
        for (int r = 0; r < 4; ++r) {
            const int o = obq + ot * 16 + agrp * 4 + r;
            const float bs = bias[o];
            float4 v;
            v.x = acc[0][ot][r] + bs;
            v.y = acc[1][ot][r] + bs;
            v.z = acc[2][ot][r] + bs;
            v.w = acc[3][ot][r] + bs;
            const long long idx = ((long long)b * storeO + o) * np + p0;
            if (OUTBF == 0) {
                *(float4*)&((float*)outv)[idx] = v;
            } else {
                *(uint2*)&((unsigned short*)outv)[idx] =
                    make_uint2(pack_bf2(v.x, v.y), pack_bf2(v.z, v.w));
            }
        }
    }
}

// ---------------------------------------------------------------------------
// Merged am + attention kernel.  am now runs at HALF-QUAD granularity:
// blocks 0..575, each wave covers 32 px (i in {0,1}) -> 2.25 blocks/CU,
// ~9 waves/CU during the am phase (was 1.1 blocks/CU, 4.5 waves).
// Per-element arithmetic identical.  attn path r12-exact (unchanged).
// ---------------------------------------------------------------------------
__global__ __launch_bounds__(256) void k_am_attn(
    const unsigned short* __restrict__ dw, const unsigned* __restrict__ pw,
    const float* __restrict__ b1v, const float* __restrict__ b2v,
    const unsigned short* __restrict__ q, const float* __restrict__ kv,
    unsigned short* __restrict__ hilo)
{
    __shared__ __align__(16) char smem[53760];
    const int bid = blockIdx.x;
    const int tid = threadIdx.x;
    const int lane = tid & 63, wid = tid >> 6;

    if (bid < 576) {
        // ================= am path (half-quad per wave) =================
        uint2* abuf = (uint2*)smem;            // 4 waves * 512 uint2 = 16KB
        const int arow = lane & 15, agrp = lane >> 4;

        const int hqi = bid * 4 + wid;         // 0..2303
        const int b   = hqi / 288;
        const int t288 = hqi % 288;
        const int quad = t288 >> 1, half = t288 & 1;
        const int pp = quad * 64 + arow * 4 + half * 2;   // 2-px base

        bf8 afr1[4][2], afr2[4][2];
#pragma unroll
        for (int ot = 0; ot < 4; ++ot)
#pragma unroll
            for (int kt = 0; kt < 2; ++kt) {
                uint4 t1 = *(const uint4*)&pw[PW_AM1 + (ot * 16 + arow) * 32 + kt * 16 + agrp * 4];
                uint4 t2 = *(const uint4*)&pw[PW_AM2 + (ot * 16 + arow) * 32 + kt * 16 + agrp * 4];
                afr1[ot][kt] = __builtin_bit_cast(bf8, t1);
                afr2[ot][kt] = __builtin_bit_cast(bf8, t2);
            }

        const unsigned short* xq = dw + (long long)b * (192ll * NP);
        const unsigned short* xk = xq + 64ll * NP;
        const unsigned short* xv = xq + 128ll * NP;

        f4 acc1[2][4];
#pragma unroll
        for (int i = 0; i < 2; ++i)
#pragma unroll
            for (int ot = 0; ot < 4; ++ot) acc1[i][ot] = (f4){0.f, 0.f, 0.f, 0.f};

#pragma unroll
        for (int kt = 0; kt < 2; ++kt) {
            const long long cbase = kt * 32 + agrp * 8;
            int uu[2][4];
#pragma unroll
            for (int jj = 0; jj < 4; ++jj) {
                ushort2 a0 = *(const ushort2*)&xq[(cbase + 2 * jj) * NP + pp];
                ushort2 a1 = *(const ushort2*)&xq[(cbase + 2 * jj + 1) * NP + pp];
                ushort2 y0 = *(const ushort2*)&xk[(cbase + 2 * jj) * NP + pp];
                ushort2 y1 = *(const ushort2*)&xk[(cbase + 2 * jj + 1) * NP + pp];
                uu[0][jj] = (int)pack_bf2(bf2f(a0.x) * bf2f(y0.x), bf2f(a1.x) * bf2f(y1.x));
                uu[1][jj] = (int)pack_bf2(bf2f(a0.y) * bf2f(y0.y), bf2f(a1.y) * bf2f(y1.y));
            }
#pragma unroll
            for (int i = 0; i < 2; ++i) {
                int4 ti = {uu[i][0], uu[i][1], uu[i][2], uu[i][3]};
                bf8 bfr = __builtin_bit_cast(bf8, ti);
#pragma unroll
                for (int ot = 0; ot < 4; ++ot)
                    acc1[i][ot] = __builtin_amdgcn_mfma_f32_16x16x32_bf16(afr1[ot][kt], bfr, acc1[i][ot], 0, 0, 0);
            }
        }

#pragma unroll
        for (int i = 0; i < 2; ++i)
#pragma unroll
            for (int ot = 0; ot < 4; ++ot) {
                const int ch0 = ot * 16 + agrp * 4;
                float v0 = acc1[i][ot][0] + b1v[ch0 + 0];
                float v1 = acc1[i][ot][1] + b1v[ch0 + 1];
                float v2 = acc1[i][ot][2] + b1v[ch0 + 2];
                float v3 = acc1[i][ot][3] + b1v[ch0 + 3];
                v0 = v0 / (1.f + __expf(-v0));
                v1 = v1 / (1.f + __expf(-v1));
                v2 = v2 / (1.f + __expf(-v2));
                v3 = v3 / (1.f + __expf(-v3));
                const int c2 = ot * 4 + agrp;
                abuf[wid * 512 + (arow * 2 + i) * 16 + (c2 ^ arow)] =
                    make_uint2(pack_bf2(v0, v1), pack_bf2(v2, v3));
            }

        f4 acc2[2][4];
#pragma unroll
        for (int i = 0; i < 2; ++i)
#pragma unroll
            for (int ot = 0; ot < 4; ++ot) acc2[i][ot] = (f4){0.f, 0.f, 0.f, 0.f};

#pragma unroll
        for (int kt = 0; kt < 2; ++kt) {
            const int bc2 = kt * 8 + agrp * 2;
#pragma unroll
            for (int i = 0; i < 2; ++i) {
                const uint2 rA = abuf[wid * 512 + (arow * 2 + i) * 16 + (bc2 ^ arow)];
                const uint2 rB = abuf[wid * 512 + (arow * 2 + i) * 16 + ((bc2 + 1) ^ arow)];
                int4 ti = make_int4((int)rA.x, (int)rA.y, (int)rB.x, (int)rB.y);
                bf8 bfr = __builtin_bit_cast(bf8, ti);
#pragma unroll
                for (int ot = 0; ot < 4; ++ot)
                    acc2[i][ot] = __builtin_amdgcn_mfma_f32_16x16x32_bf16(afr2[ot][kt], bfr, acc2[i][ot], 0, 0, 0);
            }
        }

#pragma unroll
        for (int ot = 0; ot < 4; ++ot) {
#pragma unroll
            for (int r = 0; r < 4; ++r) {
                const int o = ot * 16 + agrp * 4 + r;
                const float bs = b2v[o];
                ushort2 vv2 = *(const ushort2*)&xv[(long long)o * NP + pp];
                float h0 = tanhf((acc2[0][ot][r] + bs) * 0.25f) * bf2f(vv2.x);
                float h1 = tanhf((acc2[1][ot][r] + bs) * 0.25f) * bf2f(vv2.y);
                *(unsigned*)&hilo[((long long)b * 128 + o) * NP + pp] = pack_bf2(h0, h1);
            }
        }
        return;
    }

    // ================= attn path (r12-exact logic) =================
    int4*  klds4 = (int4*)smem;
    int4*  zlds4 = (int4*)(smem + 18432);
    int4*  vlds4 = (int4*)(smem + 18944);
    uint2* elds2 = (uint2*)(smem + 37376);

    const int flat = bid - 576;
    const int bx = flat % 72, bh = flat / 72;
    const int g = lane >> 4, qi = lane & 15;
    const int b = bh >> 2, h = bh & 3;

    const float* kbase = kv + ((long long)b * 128 + h * 16) * NPK;
    const float* vbase = kv + ((long long)b * 128 + 64 + h * 16) * NPK;

    for (int i = tid; i < 1152; i += 256) {
        const int key = i >> 1, dg = i & 1;
        const float* kp = kbase + (long long)(dg * 8) * NPK + key;
        int4 t;
        t.x = (int)pack_bf2(kp[0],       kp[NPK]);
        t.y = (int)pack_bf2(kp[2 * NPK], kp[3 * NPK]);
        t.z = (int)pack_bf2(kp[4 * NPK], kp[5 * NPK]);
        t.w = (int)pack_bf2(kp[6 * NPK], kp[7 * NPK]);
        klds4[(key >> 4) * 32 + dg * 16 + (key & 15)] = t;
    }
    for (int i = tid; i < 1152; i += 256) {
        const int t = i >> 6, l = i & 63;
        const float* vp = vbase + (long long)(l & 15) * NPK + t * 32 + (l >> 4) * 8;
        float4 a = *(const float4*)vp;
        float4 c = *(const float4*)(vp + 4);
        int4 tt;
        tt.x = (int)pack_bf2(a.x, a.y);
        tt.y = (int)pack_bf2(a.z, a.w);
        tt.z = (int)pack_bf2(c.x, c.y);
        tt.w = (int)pack_bf2(c.z, c.w);
        vlds4[i] = tt;
    }
    if (tid < 32) zlds4[tid] = make_int4(0, 0, 0, 0);
    __syncthreads();

    const int q0 = (bx * 4 + wid) * 32;
    const unsigned short* qcol = q + ((long long)b * 64 + h * 16) * NP + q0 + qi;
    int4 qv[2] = { make_int4(0, 0, 0, 0), make_int4(0, 0, 0, 0) };
    if (g < 2) {
#pragma unroll
        for (int s = 0; s < 2; ++s) {
            const unsigned short* qp = qcol + s * 16 + (long long)(g * 8) * NP;
            qv[s].x = (int)((unsigned)qp[0]          | ((unsigned)qp[(long long)NP]     << 16));
            qv[s].y = (int)((unsigned)qp[2ll * NP]   | ((unsigned)qp[3ll * NP]          << 16));
            qv[s].z = (int)((unsigned)qp[4ll * NP]   | ((unsigned)qp[5ll * NP]          << 16));
            qv[s].w = (int)((unsigned)qp[6ll * NP]   | ((unsigned)qp[7ll * NP]          << 16));
        }
    }

    f4 accp[2] = { (f4){0.f, 0.f, 0.f, 0.f}, (f4){0.f, 0.f, 0.f, 0.f} };
    float den[2] = { 0.f, 0.f };

    auto QKEXP = [&](int k2, int buf) {
#pragma unroll
        for (int tp = 0; tp < 2; ++tp) {
            const int4 kf = (lane < 32) ? klds4[(k2 * 2 + tp) * 32 + lane]
                                        : zlds4[lane & 31];
            const bf8 ka = __builtin_bit_cast(bf8, kf);
#pragma unroll
            for (int s = 0; s < 2; ++s) {
                f4 sa = __builtin_amdgcn_mfma_f32_16x16x32_bf16(
                    ka, __builtin_bit_cast(bf8, qv[s]), (f4){0.f, 0.f, 0.f, 0.f}, 0, 0, 0);
                const float e0 = __expf(sa[0]), e1 = __expf(sa[1]);
                const float e2 = __expf(sa[2]), e3 = __expf(sa[3]);
                den[s] += (e0 + e1) + (e2 + e3);
                elds2[buf * 1024 + wid * 256 + s * 128 + tp * 64 + g * 16 + qi] =
                    make_uint2(pack_bf2(e0, e1), pack_bf2(e2, e3));
            }
        }
    };
    auto PV = [&](int k2, int buf) {
        const bf8 va = __builtin_bit_cast(bf8, vlds4[k2 * 64 + lane]);
#pragma unroll
        for (int s = 0; s < 2; ++s) {
            const int base = buf * 1024 + wid * 256 + s * 128 + (g >> 1) * 64 + (g & 1) * 32 + qi;
            const uint2 r0 = elds2[base];
            const uint2 r1 = elds2[base + 16];
            int4 ti = make_int4((int)r0.x, (int)r0.y, (int)r1.x, (int)r1.y);
            accp[s] = __builtin_amdgcn_mfma_f32_16x16x32_bf16(
                va, __builtin_bit_cast(bf8, ti), accp[s], 0, 0, 0);
        }
    };

    QKEXP(0, 0);
    for (int k2 = 0; k2 < 17; ++k2) {
        QKEXP(k2 + 1, (k2 + 1) & 1);
        PV(k2, k2 & 1);
    }
    PV(17, 1);

#pragma unroll
    for (int s = 0; s < 2; ++s) {
        float d0 = den[s];
        d0 += __shfl_xor(d0, 16, 64);
        d0 += __shfl_xor(d0, 32, 64);
        const float inv = 1.0f / d0;
        unsigned short* op = hilo + ((long long)b * 128 + 64 + h * 16 + g * 4) * NP + q0 + s * 16 + qi;
#pragma unroll
        for (int r = 0; r < 4; ++r)
            op[(long long)r * NP] = f2bfu(accp[s][r] * inv);
    }
}

// ---------------------------------------------------------------------------
// depthwise 5x5, pad 2 — row-tiled LDS staging. (unchanged from r19)
// ---------------------------------------------------------------------------
__global__ __launch_bounds__(256) void k_dwconv5_lds(
    const unsigned short* __restrict__ in, const float* __restrict__ w,
    const float* __restrict__ bias, unsigned short* __restrict__ out, int ch_total)
{
    __shared__ __align__(16) float img[36 * WW];   // 13824 B
    const int tid = threadIdx.x;
    const int ch  = blockIdx.x;
    const int rt  = blockIdx.y;
    const int b   = blockIdx.z;
    const unsigned short* ip = in + ((long long)b * ch_total + ch) * NP;

    const int gr0 = rt * 32 - 2;
    for (int idx = tid; idx < 864; idx += 256) {
        const int rr = idx / 24, c4 = (idx - rr * 24) * 4;
        const int gr = gr0 + rr;
        float4 f;
        if (gr >= 0 && gr < HH) {
            const uint2 rv = *(const uint2*)&ip[gr * WW + c4];
            f.x = bflo(rv.x); f.y = bfhi(rv.x);
            f.z = bflo(rv.y); f.w = bfhi(rv.y);
        } else {
            f = make_float4(0.f, 0.f, 0.f, 0.f);
        }
        *(float4*)&img[rr * WW + c4] = f;
    }
    __syncthreads();

    const float* wp = w + ch * 25;
    float wr[25];
#pragma unroll
    for (int i = 0; i < 25; ++i) wr[i] = wp[i];
    const float bs = bias[ch];

    unsigned short* op = out + ((long long)b * ch_total + ch) * NP + rt * 32 * WW;

#pragma unroll
    for (int j = 0; j < 3; ++j) {
        const int q  = tid + 256 * j;
        const int yl = q / 24;
        const int x4 = (q - yl * 24) * 4;
        float o0 = bs, o1 = bs, o2 = bs, o3 = bs;
#pragma unroll
        for (int ky = 0; ky < 5; ++ky) {
            const float* row = &img[(yl + ky) * WW + x4];
            float4 mid = *(const float4*)row;
            float4 lf  = (x4 >= 4)      ? *(const float4*)(row - 4)
                                        : make_float4(0.f, 0.f, 0.f, 0.f);
            float4 rtv = (x4 + 4 < WW)  ? *(const float4*)(row + 4)
                                        : make_float4(0.f, 0.f, 0.f, 0.f);
            const float f0 = lf.z,  f1 = lf.w;
            const float f2 = mid.x, f3 = mid.y, f4v = mid.z, f5 = mid.w;
            const float f6 = rtv.x, f7 = rtv.y;
            const float w0 = wr[ky * 5 + 0], w1 = wr[ky * 5 + 1],
                        w2 = wr[ky * 5 + 2], w3 = wr[ky * 5 + 3],
                        w4 = wr[ky * 5 + 4];
            o0 = fmaf(w0, f0, o0); o0 = fmaf(w1, f1, o0); o0 = fmaf(w2, f2, o0);
            o0 = fmaf(w3, f3, o0); o0 = fmaf(w4, f4v, o0);
            o1 = fmaf(w0, f1, o1); o1 = fmaf(w1, f2, o1); o1 = fmaf(w2, f3, o1);
            o1 = fmaf(w3, f4v, o1); o1 = fmaf(w4, f5, o1);
            o2 = fmaf(w0, f2, o2); o2 = fmaf(w1, f3, o2); o2 = fmaf(w2, f4v, o2);
            o2 = fmaf(w3, f5, o2); o2 = fmaf(w4, f6, o2);
            o3 = fmaf(w0, f3, o3); o3 = fmaf(w1, f4v, o3); o3 = fmaf(w2, f5, o3);
            o3 = fmaf(w3, f6, o3); o3 = fmaf(w4, f7, o3);
        }
        *(uint2*)&op[yl * WW + x4] = make_uint2(pack_bf2(o0, o1), pack_bf2(o2, o3));
    }
}

// ---------------------------------------------------------------------------
// 4x4 average pool — float4 loads.  (unchanged)
// ---------------------------------------------------------------------------
__global__ __launch_bounds__(256) void k_avgpool4(
    const float* __restrict__ in, float* __restrict__ out)
{
    int idx = blockIdx.x * 256 + threadIdx.x;
    int total = NB * 128 * NPK;
    if (idx >= total) return;
    int pw = idx % 24;
    int t  = idx / 24;
    int ph = t % 24;  t /= 24;
    int c  = t % 128;
    int b  = t / 128;
    const float* ip = in + ((long long)b * 128 + c) * NP + (ph * 4) * WW + pw * 4;
    float4 r0 = *(const float4*)(ip);
    float4 r1 = *(const float4*)(ip + WW);
    float4 r2 = *(const float4*)(ip + 2 * WW);
    float4 r3 = *(const float4*)(ip + 3 * WW);
    float s = ((r0.x + r0.y) + (r0.z + r0.w)) + ((r1.x + r1.y) + (r1.z + r1.w))
            + ((r2.x + r2.y) + (r2.z + r2.w)) + ((r3.x + r3.y) + (r3.z + r3.w));
    out[idx] = s * (1.0f / 16.0f);
}

// ---------------------------------------------------------------------------
extern "C" void kernel_launch(void* const* d_in, const int* in_sizes, int n_in,
                              void* d_out, int out_size, void* d_ws, size_t ws_size,
                              hipStream_t stream)
{
    const float* x      = (const float*)d_in[0];
    const float* qkv_w  = (const float*)d_in[1];
    const float* qkv_b  = (const float*)d_in[2];
    const float* dw_w   = (const float*)d_in[3];
    const float* dw_b   = (const float*)d_in[4];
    const float* am_w1  = (const float*)d_in[5];
    const float* am_b1  = (const float*)d_in[6];
    const float* am_w2  = (const float*)d_in[7];
    const float* am_b2  = (const float*)d_in[8];
    const float* gq_w   = (const float*)d_in[9];
    const float* gq_b   = (const float*)d_in[10];
    const float* gkv_w  = (const float*)d_in[11];
    const float* gkv_b  = (const float*)d_in[12];
    const float* proj_w = (const float*)d_in[13];
    const float* proj_b = (const float*)d_in[14];
    float* out = (float*)d_out;
    char* wsb = (char*)d_ws;

    unsigned short* t_qkv  = (unsigned short*)wsb;
    unsigned short* t_hilo = (unsigned short*)wsb;
    unsigned short* t_dw   = (unsigned short*)(wsb + 28311552);
    unsigned short* t_gq   = (unsigned short*)(wsb + 56623104);
    float*          t_pool = (float*)(wsb + 66060288);
    float*          t_gkv  = (float*)(wsb + 68419584);
    unsigned*       t_pw   = (unsigned*)(wsb + 70778880);

    // 0. pre-pack all conv weights (gq scaled 0.25)
    k_packw<<<dim3((PW_TOTAL + 255) / 256), 256, 0, stream>>>(
        qkv_w, gq_w, gkv_w, am_w1, am_w2, proj_w, t_pw);
    // 1. qkv (bf16) + gq (bf16, *0.25) from one LDS-staged read of x
    k_qkvgq<<<dim3(144, 1, NB), 256, 0, stream>>>(
        x, t_pw, qkv_b, gq_b, t_qkv, t_gq);
    // 2. depthwise 5x5 (bf16 in -> bf16 out), row-tiled
    k_dwconv5_lds<<<dim3(192, 3, NB), 256, 0, stream>>>(t_qkv, dw_w, dw_b, t_dw, 192);
    // 3. pooled = avgpool4(x)
    k_avgpool4<<<dim3((NB*128*NPK + 255)/256), 256, 0, stream>>>(x, t_pool);
    // 4. gkv = conv1x1(pooled)  f32 out
    k_mfma_conv<128,4,0,0><<<dim3(3,2,NB), 256, 0, stream>>>(
        t_pool, t_pw + PW_GKV, gkv_b, t_gkv, NPK, (long long)128 * NPK, 128);
    // 5+6. merged am (blocks 0..575, half-quad waves) + attention (576..2879)
    k_am_attn<<<dim3(2880), 256, 0, stream>>>(
        t_dw, t_pw, am_b1, am_b2, t_gq, t_gkv, t_hilo);
    // 7. out = conv1x1(hilo bf16, proj_w)  f32 out
    k_mfma_conv<128,4,1,0><<<dim3(36,2,NB), 256, 0, stream>>>(
        t_hilo, t_pw + PW_PROJ, proj_b, out, NP, (long long)128 * NP, 128);
}